// Round 4
// baseline (349.298 us; speedup 1.0000x reference)
//
#include <hip/hip_runtime.h>
#include <math.h>

#define N_NODES 100000
#define N_EDGES 1600000
#define IN_DIM 128
#define HEADS 4
#define OUT_DIM 32
#define HD 128  // HEADS*OUT_DIM
#define NEG_SLOPE 0.2f
#define SCAN_NBLK 98  // ceil(100000/1024)

typedef __attribute__((ext_vector_type(8))) short short8;
typedef __attribute__((ext_vector_type(4))) float f32x4;

__device__ inline ushort f2bf(float f) {
    // round-to-nearest-even fp32 -> bf16
    uint u = __float_as_uint(f);
    u += 0x7fffu + ((u >> 16) & 1u);
    return (ushort)(u >> 16);
}

// ---------------- K1: x_proj = x @ W^T  (bf16 MFMA, fused att-dots) ----------------
// Block: 256 threads (4 waves). Tile: 64 rows x 128 cols, K=128.
// LDS: lA = 64x128 bf16 A-tile (reused as out-tile), lB = 128x128 bf16 W-tile.
// Both XOR-swizzled (byte ^= (row&7)<<4) so ds_read_b128 fragments are ~conflict-free.
__global__ __launch_bounds__(256) void k_gemm(const float* __restrict__ x,
                                              const float* __restrict__ W,
                                              ushort* __restrict__ xp,
                                              const float* __restrict__ att_src,
                                              const float* __restrict__ att_dst,
                                              float* __restrict__ asrc,
                                              float* __restrict__ adst) {
    __shared__ ushort lA[64 * 128];   // 16 KB
    __shared__ ushort lB[128 * 128];  // 32 KB
    const int tid = threadIdx.x;
    const long row_base = (long)blockIdx.x * 64;

    // ---- stage A (x rows, fp32 -> bf16, swizzled) ----
    {
        const int r = tid >> 2;
        const int c0 = (tid & 3) * 32;
        const long row = row_base + r;
        const float* src = x + row * IN_DIM + c0;
#pragma unroll
        for (int i = 0; i < 4; i++) {  // 8 cols per iter
            float4 va, vb;
            if (row < N_NODES) {
                va = *(const float4*)(src + 8 * i);
                vb = *(const float4*)(src + 8 * i + 4);
            } else {
                va = make_float4(0.f, 0.f, 0.f, 0.f);
                vb = va;
            }
            ushort h[8] = {f2bf(va.x), f2bf(va.y), f2bf(va.z), f2bf(va.w),
                           f2bf(vb.x), f2bf(vb.y), f2bf(vb.z), f2bf(vb.w)};
            uint byte = (uint)(r * 256 + (c0 + 8 * i) * 2);
            byte ^= (uint)((r & 7) << 4);
            *(uint4*)((char*)lA + byte) = *(const uint4*)h;
        }
    }
    // ---- stage B (W rows, fp32 -> bf16, swizzled): lB[c][k] = W[c][k] ----
    {
        const int c = tid >> 1;
        const int k0 = (tid & 1) * 64;
        const float* src = W + c * IN_DIM + k0;
#pragma unroll
        for (int i = 0; i < 8; i++) {  // 8 k per iter
            float4 va = *(const float4*)(src + 8 * i);
            float4 vb = *(const float4*)(src + 8 * i + 4);
            ushort h[8] = {f2bf(va.x), f2bf(va.y), f2bf(va.z), f2bf(va.w),
                           f2bf(vb.x), f2bf(vb.y), f2bf(vb.z), f2bf(vb.w)};
            uint byte = (uint)(c * 256 + (k0 + 8 * i) * 2);
            byte ^= (uint)((c & 7) << 4);
            *(uint4*)((char*)lB + byte) = *(const uint4*)h;
        }
    }
    __syncthreads();

    // ---- MFMA main: wave w owns rows w*16..w*16+15, all 128 cols ----
    const int w = tid >> 6;
    const int lane = tid & 63;
    const int l15 = lane & 15;
    const int g8 = (lane >> 4) * 8;  // k sub-offset (consistent convention for A and B)
    const int arow = w * 16 + l15;

    f32x4 acc[8];
#pragma unroll
    for (int nt = 0; nt < 8; nt++) acc[nt] = (f32x4){0.f, 0.f, 0.f, 0.f};

#pragma unroll
    for (int t = 0; t < 4; t++) {
        uint ab = (uint)(arow * 256 + (t * 32 + g8) * 2);
        ab ^= (uint)((arow & 7) << 4);
        short8 af = *(const short8*)((const char*)lA + ab);
#pragma unroll
        for (int nt = 0; nt < 8; nt++) {
            int c = nt * 16 + l15;
            uint bb = (uint)(c * 256 + (t * 32 + g8) * 2);
            bb ^= (uint)((c & 7) << 4);
            short8 bfr = *(const short8*)((const char*)lB + bb);
            acc[nt] = __builtin_amdgcn_mfma_f32_16x16x32_bf16(af, bfr, acc[nt], 0, 0, 0);
        }
    }
    __syncthreads();  // done reading lA/lB; reuse lA as out-tile

    // ---- write acc -> lA (linear [64][128] bf16 out-tile) ----
    // C/D layout: col = lane&15, row = 4*(lane>>4)+reg  [m89/m91]
    {
        const int m4 = 4 * (lane >> 4);
#pragma unroll
        for (int nt = 0; nt < 8; nt++) {
            int c = nt * 16 + l15;
#pragma unroll
            for (int r = 0; r < 4; r++) {
                lA[(w * 16 + m4 + r) * 128 + c] = f2bf(acc[nt][r]);
            }
        }
    }
    __syncthreads();

    // ---- epilogue: coalesced xp store + fused attention dots ----
    {
        const int r = tid >> 2;
        const long node = row_base + r;
        if (node < N_NODES) {
            const int h = tid & 3;
            const int c0 = h * 32;
            const uint4* s = (const uint4*)(lA + r * 128 + c0);
            uint4 v0 = s[0], v1 = s[1], v2 = s[2], v3 = s[3];
            uint4* d = (uint4*)(xp + node * HD + c0);
            d[0] = v0; d[1] = v1; d[2] = v2; d[3] = v3;
            // att dots over this head's 32 cols (values already in regs)
            const float* as = att_src + c0;
            const float* ad = att_dst + c0;
            float s0 = 0.f, s1 = 0.f;
            uint4 vv[4] = {v0, v1, v2, v3};
#pragma unroll
            for (int q = 0; q < 4; q++) {
                const uint* u = (const uint*)&vv[q];
#pragma unroll
                for (int p = 0; p < 4; p++) {
                    float f0 = __uint_as_float((u[p] & 0xffffu) << 16);
                    float f1 = __uint_as_float(u[p] & 0xffff0000u);
                    int cc = q * 8 + p * 2;
                    s0 = fmaf(f0, as[cc], s0);
                    s0 = fmaf(f1, as[cc + 1], s0);
                    s1 = fmaf(f0, ad[cc], s1);
                    s1 = fmaf(f1, ad[cc + 1], s1);
                }
            }
            asrc[node * HEADS + h] = s0;
            adst[node * HEADS + h] = s1;
        }
    }
}

// ---------------- K2: per-dst edge counts (4 edges/thread) ----------------
__global__ void k_count(const int* __restrict__ ei, int* __restrict__ cnt) {
    int t = blockIdx.x * 256 + threadIdx.x;
    int e = t * 4;
    if (e + 4 <= N_EDGES) {
        int4 d = *(const int4*)(ei + N_EDGES + e);
        atomicAdd(&cnt[d.x], 1);
        atomicAdd(&cnt[d.y], 1);
        atomicAdd(&cnt[d.z], 1);
        atomicAdd(&cnt[d.w], 1);
    } else {
        for (; e < N_EDGES; e++) atomicAdd(&cnt[ei[N_EDGES + e]], 1);
    }
}

// ---------------- K3: exclusive scan of counts (3 kernels) ----------------
__global__ __launch_bounds__(256) void k_scan1(const int* __restrict__ cnt,
                                               int* __restrict__ row_start,
                                               int* __restrict__ partial) {
    __shared__ int lds[256];
    int t = threadIdx.x;
    int base = blockIdx.x * 1024 + t * 4;
    int c0 = (base + 0 < N_NODES) ? cnt[base + 0] : 0;
    int c1 = (base + 1 < N_NODES) ? cnt[base + 1] : 0;
    int c2 = (base + 2 < N_NODES) ? cnt[base + 2] : 0;
    int c3 = (base + 3 < N_NODES) ? cnt[base + 3] : 0;
    int p1 = c0, p2 = c0 + c1, p3 = c0 + c1 + c2;
    int tsum = p3 + c3;
    lds[t] = tsum;
    __syncthreads();
    for (int off = 1; off < 256; off <<= 1) {
        int v = (t >= off) ? lds[t - off] : 0;
        __syncthreads();
        lds[t] += v;
        __syncthreads();
    }
    int excl = (t == 0) ? 0 : lds[t - 1];
    if (base + 0 < N_NODES) row_start[base + 0] = excl;
    if (base + 1 < N_NODES) row_start[base + 1] = excl + p1;
    if (base + 2 < N_NODES) row_start[base + 2] = excl + p2;
    if (base + 3 < N_NODES) row_start[base + 3] = excl + p3;
    if (t == 255) partial[blockIdx.x] = lds[255];
}

__global__ __launch_bounds__(128) void k_scan2(int* __restrict__ partial) {
    __shared__ int lds[128];
    int t = threadIdx.x;
    int v = (t < SCAN_NBLK) ? partial[t] : 0;
    lds[t] = v;
    __syncthreads();
    for (int off = 1; off < 128; off <<= 1) {
        int u = (t >= off) ? lds[t - off] : 0;
        __syncthreads();
        lds[t] += u;
        __syncthreads();
    }
    if (t < SCAN_NBLK) partial[t] = (t == 0) ? 0 : lds[t - 1];
}

__global__ void k_scan3(int* __restrict__ row_start, const int* __restrict__ partial,
                        int* __restrict__ cursor) {
    int i = blockIdx.x * 256 + threadIdx.x;
    if (i < N_NODES) {
        int rs = row_start[i] + partial[i >> 10];
        row_start[i] = rs;
        cursor[i] = rs;
    }
    if (i == 0) row_start[N_NODES] = N_EDGES;
}

// ---------------- K4: CSR scatter of src ids only (4 edges/thread) ----------------
// att logits are NOT materialized: aggregate recomputes them from asrc/adst.
__global__ void k_scatter(const int* __restrict__ ei,
                          int* __restrict__ cursor,
                          int* __restrict__ esrc) {
    int t = blockIdx.x * 256 + threadIdx.x;
    int e = t * 4;
    if (e + 4 <= N_EDGES) {
        int4 s = *(const int4*)(ei + e);
        int4 d = *(const int4*)(ei + N_EDGES + e);
        int p0 = atomicAdd(&cursor[d.x], 1);
        int p1 = atomicAdd(&cursor[d.y], 1);
        int p2 = atomicAdd(&cursor[d.z], 1);
        int p3 = atomicAdd(&cursor[d.w], 1);
        esrc[p0] = s.x;
        esrc[p1] = s.y;
        esrc[p2] = s.z;
        esrc[p3] = s.w;
    } else {
        for (; e < N_EDGES; e++) {
            int s = ei[e];
            int d = ei[N_EDGES + e];
            int pos = atomicAdd(&cursor[d], 1);
            esrc[pos] = s;
        }
    }
}

// ---------------- K5: single-pass softmax + aggregation (1 wave/node) ----------------
// xp is bf16; lane owns output elements {2*lane, 2*lane+1} (head h=lane>>4), so each
// edge's row gather is ONE ushort2-per-lane load (256 B/wave = 1 row).
// Attention logit recomputed in-register: leakyrelu(asrc4[src] + adst4[n]).
// Unnormalized exp (shift-invariant softmax; logits bounded, clamp 80).
__global__ __launch_bounds__(256) void k_aggregate(const int* __restrict__ row_start,
                                                   const int* __restrict__ esrc,
                                                   const float4* __restrict__ asrc4,
                                                   const float4* __restrict__ adst4,
                                                   const ushort* __restrict__ xp,
                                                   const float* __restrict__ bias,
                                                   float* __restrict__ out) {
    const int wid = threadIdx.x >> 6;
    const int lane = threadIdx.x & 63;
    const int n = blockIdx.x * 4 + wid;
    if (n >= N_NODES) return;
    const int s0 = row_start[n];
    const int s1 = row_start[n + 1];
    const int h = lane >> 4;
    const float4 ad = adst4[n];  // wave-uniform

    float acc0 = 0.f, acc1 = 0.f, den = 0.f;

    for (int base = s0; base < s1; base += 64) {
        const int rem = s1 - base;
        const int cnt = rem < 64 ? rem : 64;
        const bool v = lane < cnt;
        int msrc = v ? esrc[base + lane] : 0;
        float4 as = asrc4[msrc];
        float tx = as.x + ad.x, ty = as.y + ad.y, tz = as.z + ad.z, tw = as.w + ad.w;
        tx = (tx >= 0.f) ? tx : NEG_SLOPE * tx;
        ty = (ty >= 0.f) ? ty : NEG_SLOPE * ty;
        tz = (tz >= 0.f) ? tz : NEG_SLOPE * tz;
        tw = (tw >= 0.f) ? tw : NEG_SLOPE * tw;
        float wx = v ? __expf(fminf(tx, 80.f)) : 0.f;
        float wy = v ? __expf(fminf(ty, 80.f)) : 0.f;
        float wz = v ? __expf(fminf(tz, 80.f)) : 0.f;
        float ww = v ? __expf(fminf(tw, 80.f)) : 0.f;

        int j = 0;
        for (; j + 4 <= cnt; j += 4) {
            const uint* p[4];
            float ee[4];
#pragma unroll
            for (int u = 0; u < 4; u++) {
                int src = __shfl(msrc, j + u);
                float a = __shfl(wx, j + u);
                float b = __shfl(wy, j + u);
                float c = __shfl(wz, j + u);
                float d = __shfl(ww, j + u);
                float lo = (h & 1) ? b : a;
                float hi = (h & 1) ? d : c;
                ee[u] = (h & 2) ? hi : lo;
                p[u] = (const uint*)(xp + (long)src * HD) + lane;
            }
            uint g[4];
#pragma unroll
            for (int u = 0; u < 4; u++) g[u] = *p[u];
#pragma unroll
            for (int u = 0; u < 4; u++) {
                float f0 = __uint_as_float((g[u] & 0xffffu) << 16);
                float f1 = __uint_as_float(g[u] & 0xffff0000u);
                den += ee[u];
                acc0 = fmaf(ee[u], f0, acc0);
                acc1 = fmaf(ee[u], f1, acc1);
            }
        }
        for (; j < cnt; j++) {
            int src = __shfl(msrc, j);
            float a = __shfl(wx, j);
            float b = __shfl(wy, j);
            float c = __shfl(wz, j);
            float d = __shfl(ww, j);
            float lo = (h & 1) ? b : a;
            float hi = (h & 1) ? d : c;
            float e = (h & 2) ? hi : lo;
            uint g = *((const uint*)(xp + (long)src * HD) + lane);
            float f0 = __uint_as_float((g & 0xffffu) << 16);
            float f1 = __uint_as_float(g & 0xffff0000u);
            den += e;
            acc0 = fmaf(e, f0, acc0);
            acc1 = fmaf(e, f1, acc1);
        }
    }
    float inv = 1.f / (den + 1e-12f);
    float2 b2 = ((const float2*)bias)[lane];
    float2 o;
    o.x = acc0 * inv + b2.x;
    o.y = acc1 * inv + b2.y;
    ((float2*)(out + (long)n * HD))[lane] = o;
}

extern "C" void kernel_launch(void* const* d_in, const int* in_sizes, int n_in,
                              void* d_out, int out_size, void* d_ws, size_t ws_size,
                              hipStream_t stream) {
    const float* x = (const float*)d_in[0];
    const int* ei = (const int*)d_in[1];
    const float* W = (const float*)d_in[2];
    const float* att_src = (const float*)d_in[3];
    const float* att_dst = (const float*)d_in[4];
    const float* bias = (const float*)d_in[5];
    float* out = (float*)d_out;
    char* ws = (char*)d_ws;

    // workspace layout (bytes), 16B-aligned
    ushort* xp       = (ushort*)(ws + 0);         // 25,600,000 (bf16 x_proj)
    float* asrc      = (float*)(ws + 25600000);   //  1,600,000
    float* adst      = (float*)(ws + 27200000);   //  1,600,000
    int* esrc        = (int*)(ws + 28800000);     //  6,400,000
    int* cnt         = (int*)(ws + 35200000);     //    400,000
    int* row_start   = (int*)(ws + 35600000);     //    400,004
    int* cursor      = (int*)(ws + 36000016);     //    400,000
    int* partial     = (int*)(ws + 36400016);     //        512
    // total ~36.4 MB

    hipMemsetAsync(cnt, 0, N_NODES * sizeof(int), stream);
    k_gemm<<<(N_NODES + 63) / 64, 256, 0, stream>>>(x, W, xp, att_src, att_dst, asrc, adst);
    k_count<<<(N_EDGES / 4 + 255) / 256, 256, 0, stream>>>(ei, cnt);
    k_scan1<<<SCAN_NBLK, 256, 0, stream>>>(cnt, row_start, partial);
    k_scan2<<<1, 128, 0, stream>>>(partial);
    k_scan3<<<(N_NODES + 255) / 256, 256, 0, stream>>>(row_start, partial, cursor);
    k_scatter<<<(N_EDGES / 4 + 255) / 256, 256, 0, stream>>>(ei, cursor, esrc);
    k_aggregate<<<(N_NODES + 3) / 4, 256, 0, stream>>>(row_start, esrc,
                                                       (const float4*)asrc, (const float4*)adst,
                                                       xp, bias, out);
}

// Round 5
// 324.666 us; speedup vs baseline: 1.0759x; 1.0759x over previous
//
#include <hip/hip_runtime.h>
#include <math.h>

#define N_NODES 100000
#define N_EDGES 1600000
#define IN_DIM 128
#define HEADS 4
#define OUT_DIM 32
#define HD 128  // HEADS*OUT_DIM
#define NEG_SLOPE 0.2f
#define SCAN_NBLK 98  // ceil(100000/1024)

typedef __attribute__((ext_vector_type(8))) short short8;
typedef __attribute__((ext_vector_type(4))) float f32x4;

__device__ inline ushort f2bf(float f) {
    // round-to-nearest-even fp32 -> bf16
    uint u = __float_as_uint(f);
    u += 0x7fffu + ((u >> 16) & 1u);
    return (ushort)(u >> 16);
}

// ---------------- K1: x_proj = x @ W^T  (bf16 MFMA, fused att-dots) ----------------
// Block: 256 threads (4 waves). Tile: 64 rows x 128 cols, K=128.
// LDS: lA = 64x128 bf16 A-tile (reused as out-tile), lB = 128x128 bf16 W-tile.
// Both XOR-swizzled (byte ^= (row&7)<<4) so ds_read_b128 fragments are ~conflict-free.
__global__ __launch_bounds__(256) void k_gemm(const float* __restrict__ x,
                                              const float* __restrict__ W,
                                              ushort* __restrict__ xp,
                                              const float* __restrict__ att_src,
                                              const float* __restrict__ att_dst,
                                              float* __restrict__ asrc,
                                              float* __restrict__ adst) {
    __shared__ ushort lA[64 * 128];   // 16 KB
    __shared__ ushort lB[128 * 128];  // 32 KB
    const int tid = threadIdx.x;
    const long row_base = (long)blockIdx.x * 64;

    // ---- stage A (x rows, fp32 -> bf16, swizzled) ----
    {
        const int r = tid >> 2;
        const int c0 = (tid & 3) * 32;
        const long row = row_base + r;
        const float* src = x + row * IN_DIM + c0;
#pragma unroll
        for (int i = 0; i < 4; i++) {  // 8 cols per iter
            float4 va, vb;
            if (row < N_NODES) {
                va = *(const float4*)(src + 8 * i);
                vb = *(const float4*)(src + 8 * i + 4);
            } else {
                va = make_float4(0.f, 0.f, 0.f, 0.f);
                vb = va;
            }
            ushort h[8] = {f2bf(va.x), f2bf(va.y), f2bf(va.z), f2bf(va.w),
                           f2bf(vb.x), f2bf(vb.y), f2bf(vb.z), f2bf(vb.w)};
            uint byte = (uint)(r * 256 + (c0 + 8 * i) * 2);
            byte ^= (uint)((r & 7) << 4);
            *(uint4*)((char*)lA + byte) = *(const uint4*)h;
        }
    }
    // ---- stage B (W rows, fp32 -> bf16, swizzled): lB[c][k] = W[c][k] ----
    {
        const int c = tid >> 1;
        const int k0 = (tid & 1) * 64;
        const float* src = W + c * IN_DIM + k0;
#pragma unroll
        for (int i = 0; i < 8; i++) {  // 8 k per iter
            float4 va = *(const float4*)(src + 8 * i);
            float4 vb = *(const float4*)(src + 8 * i + 4);
            ushort h[8] = {f2bf(va.x), f2bf(va.y), f2bf(va.z), f2bf(va.w),
                           f2bf(vb.x), f2bf(vb.y), f2bf(vb.z), f2bf(vb.w)};
            uint byte = (uint)(c * 256 + (k0 + 8 * i) * 2);
            byte ^= (uint)((c & 7) << 4);
            *(uint4*)((char*)lB + byte) = *(const uint4*)h;
        }
    }
    __syncthreads();

    // ---- MFMA main: wave w owns rows w*16..w*16+15, all 128 cols ----
    const int w = tid >> 6;
    const int lane = tid & 63;
    const int l15 = lane & 15;
    const int g8 = (lane >> 4) * 8;  // k sub-offset (consistent convention for A and B)
    const int arow = w * 16 + l15;

    f32x4 acc[8];
#pragma unroll
    for (int nt = 0; nt < 8; nt++) acc[nt] = (f32x4){0.f, 0.f, 0.f, 0.f};

#pragma unroll
    for (int t = 0; t < 4; t++) {
        uint ab = (uint)(arow * 256 + (t * 32 + g8) * 2);
        ab ^= (uint)((arow & 7) << 4);
        short8 af = *(const short8*)((const char*)lA + ab);
#pragma unroll
        for (int nt = 0; nt < 8; nt++) {
            int c = nt * 16 + l15;
            uint bb = (uint)(c * 256 + (t * 32 + g8) * 2);
            bb ^= (uint)((c & 7) << 4);
            short8 bfr = *(const short8*)((const char*)lB + bb);
            acc[nt] = __builtin_amdgcn_mfma_f32_16x16x32_bf16(af, bfr, acc[nt], 0, 0, 0);
        }
    }
    __syncthreads();  // done reading lA/lB; reuse lA as out-tile

    // ---- write acc -> lA (linear [64][128] bf16 out-tile) ----
    // C/D layout: col = lane&15, row = 4*(lane>>4)+reg  [m89/m91]
    {
        const int m4 = 4 * (lane >> 4);
#pragma unroll
        for (int nt = 0; nt < 8; nt++) {
            int c = nt * 16 + l15;
#pragma unroll
            for (int r = 0; r < 4; r++) {
                lA[(w * 16 + m4 + r) * 128 + c] = f2bf(acc[nt][r]);
            }
        }
    }
    __syncthreads();

    // ---- epilogue: coalesced xp store + fused attention dots ----
    {
        const int r = tid >> 2;
        const long node = row_base + r;
        if (node < N_NODES) {
            const int h = tid & 3;
            const int c0 = h * 32;
            const uint4* s = (const uint4*)(lA + r * 128 + c0);
            uint4 v0 = s[0], v1 = s[1], v2 = s[2], v3 = s[3];
            uint4* d = (uint4*)(xp + node * HD + c0);
            d[0] = v0; d[1] = v1; d[2] = v2; d[3] = v3;
            // att dots over this head's 32 cols (values already in regs)
            const float* as = att_src + c0;
            const float* ad = att_dst + c0;
            float s0 = 0.f, s1 = 0.f;
            uint4 vv[4] = {v0, v1, v2, v3};
#pragma unroll
            for (int q = 0; q < 4; q++) {
                const uint* u = (const uint*)&vv[q];
#pragma unroll
                for (int p = 0; p < 4; p++) {
                    float f0 = __uint_as_float((u[p] & 0xffffu) << 16);
                    float f1 = __uint_as_float(u[p] & 0xffff0000u);
                    int cc = q * 8 + p * 2;
                    s0 = fmaf(f0, as[cc], s0);
                    s0 = fmaf(f1, as[cc + 1], s0);
                    s1 = fmaf(f0, ad[cc], s1);
                    s1 = fmaf(f1, ad[cc + 1], s1);
                }
            }
            asrc[node * HEADS + h] = s0;
            adst[node * HEADS + h] = s1;
        }
    }
}

// ---------------- K2: per-dst edge counts (1 edge/thread: max TLP) ----------------
__global__ void k_count(const int* __restrict__ ei, int* __restrict__ cnt) {
    int e = blockIdx.x * 256 + threadIdx.x;
    if (e < N_EDGES) atomicAdd(&cnt[ei[N_EDGES + e]], 1);
}

// ---------------- K3: exclusive scan of counts (3 kernels) ----------------
__global__ __launch_bounds__(256) void k_scan1(const int* __restrict__ cnt,
                                               int* __restrict__ row_start,
                                               int* __restrict__ partial) {
    __shared__ int lds[256];
    int t = threadIdx.x;
    int base = blockIdx.x * 1024 + t * 4;
    int c0 = (base + 0 < N_NODES) ? cnt[base + 0] : 0;
    int c1 = (base + 1 < N_NODES) ? cnt[base + 1] : 0;
    int c2 = (base + 2 < N_NODES) ? cnt[base + 2] : 0;
    int c3 = (base + 3 < N_NODES) ? cnt[base + 3] : 0;
    int p1 = c0, p2 = c0 + c1, p3 = c0 + c1 + c2;
    int tsum = p3 + c3;
    lds[t] = tsum;
    __syncthreads();
    for (int off = 1; off < 256; off <<= 1) {
        int v = (t >= off) ? lds[t - off] : 0;
        __syncthreads();
        lds[t] += v;
        __syncthreads();
    }
    int excl = (t == 0) ? 0 : lds[t - 1];
    if (base + 0 < N_NODES) row_start[base + 0] = excl;
    if (base + 1 < N_NODES) row_start[base + 1] = excl + p1;
    if (base + 2 < N_NODES) row_start[base + 2] = excl + p2;
    if (base + 3 < N_NODES) row_start[base + 3] = excl + p3;
    if (t == 255) partial[blockIdx.x] = lds[255];
}

__global__ __launch_bounds__(128) void k_scan2(int* __restrict__ partial) {
    __shared__ int lds[128];
    int t = threadIdx.x;
    int v = (t < SCAN_NBLK) ? partial[t] : 0;
    lds[t] = v;
    __syncthreads();
    for (int off = 1; off < 128; off <<= 1) {
        int u = (t >= off) ? lds[t - off] : 0;
        __syncthreads();
        lds[t] += u;
        __syncthreads();
    }
    if (t < SCAN_NBLK) partial[t] = (t == 0) ? 0 : lds[t - 1];
}

__global__ void k_scan3(int* __restrict__ row_start, const int* __restrict__ partial,
                        int* __restrict__ cursor) {
    int i = blockIdx.x * 256 + threadIdx.x;
    if (i < N_NODES) {
        int rs = row_start[i] + partial[i >> 10];
        row_start[i] = rs;
        cursor[i] = rs;
    }
    if (i == 0) row_start[N_NODES] = N_EDGES;
}

// ---------------- K4: CSR scatter of src ids (1 edge/thread, dst-range pass) ----------------
// Range-split so each pass's esrc write region (~3.2 MB) fits the 4 MB per-XCD L2:
// dirty 64B lines accumulate ~16 4B writes before writeback instead of thrashing.
__global__ void k_scatter(const int* __restrict__ ei,
                          int* __restrict__ cursor,
                          int* __restrict__ esrc,
                          int lo, int hi) {
    int e = blockIdx.x * 256 + threadIdx.x;
    if (e >= N_EDGES) return;
    int d = ei[N_EDGES + e];
    if (d < lo || d >= hi) return;
    int s = ei[e];
    int pos = atomicAdd(&cursor[d], 1);
    esrc[pos] = s;
}

// ---------------- K5: single-pass softmax + aggregation (1 wave/node) ----------------
// xp is bf16; lane owns output elements {2*lane, 2*lane+1} (head h=lane>>4), so each
// edge's row gather is ONE ushort2-per-lane load (256 B/wave = 1 row).
// Attention logit recomputed in-register: leakyrelu(asrc4[src] + adst4[n]).
// Unnormalized exp (shift-invariant softmax; logits bounded, clamp 80).
__global__ __launch_bounds__(256) void k_aggregate(const int* __restrict__ row_start,
                                                   const int* __restrict__ esrc,
                                                   const float4* __restrict__ asrc4,
                                                   const float4* __restrict__ adst4,
                                                   const ushort* __restrict__ xp,
                                                   const float* __restrict__ bias,
                                                   float* __restrict__ out) {
    const int wid = threadIdx.x >> 6;
    const int lane = threadIdx.x & 63;
    const int n = blockIdx.x * 4 + wid;
    if (n >= N_NODES) return;
    const int s0 = row_start[n];
    const int s1 = row_start[n + 1];
    const int h = lane >> 4;
    const float4 ad = adst4[n];  // wave-uniform

    float acc0 = 0.f, acc1 = 0.f, den = 0.f;

    for (int base = s0; base < s1; base += 64) {
        const int rem = s1 - base;
        const int cnt = rem < 64 ? rem : 64;
        const bool v = lane < cnt;
        int msrc = v ? esrc[base + lane] : 0;
        float4 as = asrc4[msrc];
        float tx = as.x + ad.x, ty = as.y + ad.y, tz = as.z + ad.z, tw = as.w + ad.w;
        tx = (tx >= 0.f) ? tx : NEG_SLOPE * tx;
        ty = (ty >= 0.f) ? ty : NEG_SLOPE * ty;
        tz = (tz >= 0.f) ? tz : NEG_SLOPE * tz;
        tw = (tw >= 0.f) ? tw : NEG_SLOPE * tw;
        float wx = v ? __expf(fminf(tx, 80.f)) : 0.f;
        float wy = v ? __expf(fminf(ty, 80.f)) : 0.f;
        float wz = v ? __expf(fminf(tz, 80.f)) : 0.f;
        float ww = v ? __expf(fminf(tw, 80.f)) : 0.f;

        int j = 0;
        for (; j + 4 <= cnt; j += 4) {
            const uint* p[4];
            float ee[4];
#pragma unroll
            for (int u = 0; u < 4; u++) {
                int src = __shfl(msrc, j + u);
                float a = __shfl(wx, j + u);
                float b = __shfl(wy, j + u);
                float c = __shfl(wz, j + u);
                float d = __shfl(ww, j + u);
                float lo = (h & 1) ? b : a;
                float hi = (h & 1) ? d : c;
                ee[u] = (h & 2) ? hi : lo;
                p[u] = (const uint*)(xp + (long)src * HD) + lane;
            }
            uint g[4];
#pragma unroll
            for (int u = 0; u < 4; u++) g[u] = *p[u];
#pragma unroll
            for (int u = 0; u < 4; u++) {
                float f0 = __uint_as_float((g[u] & 0xffffu) << 16);
                float f1 = __uint_as_float(g[u] & 0xffff0000u);
                den += ee[u];
                acc0 = fmaf(ee[u], f0, acc0);
                acc1 = fmaf(ee[u], f1, acc1);
            }
        }
        for (; j < cnt; j++) {
            int src = __shfl(msrc, j);
            float a = __shfl(wx, j);
            float b = __shfl(wy, j);
            float c = __shfl(wz, j);
            float d = __shfl(ww, j);
            float lo = (h & 1) ? b : a;
            float hi = (h & 1) ? d : c;
            float e = (h & 2) ? hi : lo;
            uint g = *((const uint*)(xp + (long)src * HD) + lane);
            float f0 = __uint_as_float((g & 0xffffu) << 16);
            float f1 = __uint_as_float(g & 0xffff0000u);
            den += e;
            acc0 = fmaf(e, f0, acc0);
            acc1 = fmaf(e, f1, acc1);
        }
    }
    float inv = 1.f / (den + 1e-12f);
    float2 b2 = ((const float2*)bias)[lane];
    float2 o;
    o.x = acc0 * inv + b2.x;
    o.y = acc1 * inv + b2.y;
    ((float2*)(out + (long)n * HD))[lane] = o;
}

extern "C" void kernel_launch(void* const* d_in, const int* in_sizes, int n_in,
                              void* d_out, int out_size, void* d_ws, size_t ws_size,
                              hipStream_t stream) {
    const float* x = (const float*)d_in[0];
    const int* ei = (const int*)d_in[1];
    const float* W = (const float*)d_in[2];
    const float* att_src = (const float*)d_in[3];
    const float* att_dst = (const float*)d_in[4];
    const float* bias = (const float*)d_in[5];
    float* out = (float*)d_out;
    char* ws = (char*)d_ws;

    // workspace layout (bytes), 16B-aligned
    ushort* xp       = (ushort*)(ws + 0);         // 25,600,000 (bf16 x_proj)
    float* asrc      = (float*)(ws + 25600000);   //  1,600,000
    float* adst      = (float*)(ws + 27200000);   //  1,600,000
    int* esrc        = (int*)(ws + 28800000);     //  6,400,000
    int* cnt         = (int*)(ws + 35200000);     //    400,000
    int* row_start   = (int*)(ws + 35600000);     //    400,004
    int* cursor      = (int*)(ws + 36000016);     //    400,000
    int* partial     = (int*)(ws + 36400016);     //        512
    // total ~36.4 MB

    hipMemsetAsync(cnt, 0, N_NODES * sizeof(int), stream);
    k_gemm<<<(N_NODES + 63) / 64, 256, 0, stream>>>(x, W, xp, att_src, att_dst, asrc, adst);
    k_count<<<(N_EDGES + 255) / 256, 256, 0, stream>>>(ei, cnt);
    k_scan1<<<SCAN_NBLK, 256, 0, stream>>>(cnt, row_start, partial);
    k_scan2<<<1, 128, 0, stream>>>(partial);
    k_scan3<<<(N_NODES + 255) / 256, 256, 0, stream>>>(row_start, partial, cursor);
    k_scatter<<<(N_EDGES + 255) / 256, 256, 0, stream>>>(ei, cursor, esrc, 0, N_NODES / 2);
    k_scatter<<<(N_EDGES + 255) / 256, 256, 0, stream>>>(ei, cursor, esrc, N_NODES / 2, N_NODES);
    k_aggregate<<<(N_NODES + 3) / 4, 256, 0, stream>>>(row_start, esrc,
                                                       (const float4*)asrc, (const float4*)adst,
                                                       xp, bias, out);
}

// Round 6
// 228.346 us; speedup vs baseline: 1.5297x; 1.4218x over previous
//
#include <hip/hip_runtime.h>
#include <math.h>

#define N_NODES 100000
#define N_EDGES 1600000
#define IN_DIM 128
#define HEADS 4
#define OUT_DIM 32
#define HD 128  // HEADS*OUT_DIM
#define NEG_SLOPE 0.2f
#define SCAN_NBLK 98  // ceil(100000/1024)

typedef __attribute__((ext_vector_type(8))) short short8;
typedef __attribute__((ext_vector_type(4))) float f32x4;

__device__ inline ushort f2bf(float f) {
    // round-to-nearest-even fp32 -> bf16
    uint u = __float_as_uint(f);
    u += 0x7fffu + ((u >> 16) & 1u);
    return (ushort)(u >> 16);
}

// ---------------- K1: x_proj = x @ W^T  (bf16 MFMA, fused att-dots) ----------------
// Block: 256 threads (4 waves). Tile: 64 rows x 128 cols, K=128.
// LDS: lA = 64x128 bf16 A-tile (reused as out-tile), lB = 128x128 bf16 W-tile.
// Both XOR-swizzled (byte ^= (row&7)<<4) so ds_read_b128 fragments are ~conflict-free.
__global__ __launch_bounds__(256) void k_gemm(const float* __restrict__ x,
                                              const float* __restrict__ W,
                                              ushort* __restrict__ xp,
                                              const float* __restrict__ att_src,
                                              const float* __restrict__ att_dst,
                                              float* __restrict__ asrc,
                                              float* __restrict__ adst) {
    __shared__ ushort lA[64 * 128];   // 16 KB
    __shared__ ushort lB[128 * 128];  // 32 KB
    const int tid = threadIdx.x;
    const long row_base = (long)blockIdx.x * 64;

    // ---- stage A (x rows, fp32 -> bf16, swizzled) ----
    {
        const int r = tid >> 2;
        const int c0 = (tid & 3) * 32;
        const long row = row_base + r;
        const float* src = x + row * IN_DIM + c0;
#pragma unroll
        for (int i = 0; i < 4; i++) {  // 8 cols per iter
            float4 va, vb;
            if (row < N_NODES) {
                va = *(const float4*)(src + 8 * i);
                vb = *(const float4*)(src + 8 * i + 4);
            } else {
                va = make_float4(0.f, 0.f, 0.f, 0.f);
                vb = va;
            }
            ushort h[8] = {f2bf(va.x), f2bf(va.y), f2bf(va.z), f2bf(va.w),
                           f2bf(vb.x), f2bf(vb.y), f2bf(vb.z), f2bf(vb.w)};
            uint byte = (uint)(r * 256 + (c0 + 8 * i) * 2);
            byte ^= (uint)((r & 7) << 4);
            *(uint4*)((char*)lA + byte) = *(const uint4*)h;
        }
    }
    // ---- stage B (W rows, fp32 -> bf16, swizzled): lB[c][k] = W[c][k] ----
    {
        const int c = tid >> 1;
        const int k0 = (tid & 1) * 64;
        const float* src = W + c * IN_DIM + k0;
#pragma unroll
        for (int i = 0; i < 8; i++) {  // 8 k per iter
            float4 va = *(const float4*)(src + 8 * i);
            float4 vb = *(const float4*)(src + 8 * i + 4);
            ushort h[8] = {f2bf(va.x), f2bf(va.y), f2bf(va.z), f2bf(va.w),
                           f2bf(vb.x), f2bf(vb.y), f2bf(vb.z), f2bf(vb.w)};
            uint byte = (uint)(c * 256 + (k0 + 8 * i) * 2);
            byte ^= (uint)((c & 7) << 4);
            *(uint4*)((char*)lB + byte) = *(const uint4*)h;
        }
    }
    __syncthreads();

    // ---- MFMA main: wave w owns rows w*16..w*16+15, all 128 cols ----
    const int w = tid >> 6;
    const int lane = tid & 63;
    const int l15 = lane & 15;
    const int g8 = (lane >> 4) * 8;  // k sub-offset (consistent convention for A and B)
    const int arow = w * 16 + l15;

    f32x4 acc[8];
#pragma unroll
    for (int nt = 0; nt < 8; nt++) acc[nt] = (f32x4){0.f, 0.f, 0.f, 0.f};

#pragma unroll
    for (int t = 0; t < 4; t++) {
        uint ab = (uint)(arow * 256 + (t * 32 + g8) * 2);
        ab ^= (uint)((arow & 7) << 4);
        short8 af = *(const short8*)((const char*)lA + ab);
#pragma unroll
        for (int nt = 0; nt < 8; nt++) {
            int c = nt * 16 + l15;
            uint bb = (uint)(c * 256 + (t * 32 + g8) * 2);
            bb ^= (uint)((c & 7) << 4);
            short8 bfr = *(const short8*)((const char*)lB + bb);
            acc[nt] = __builtin_amdgcn_mfma_f32_16x16x32_bf16(af, bfr, acc[nt], 0, 0, 0);
        }
    }
    __syncthreads();  // done reading lA/lB; reuse lA as out-tile

    // ---- write acc -> lA (linear [64][128] bf16 out-tile) ----
    // C/D layout: col = lane&15, row = 4*(lane>>4)+reg  [m89/m91]
    {
        const int m4 = 4 * (lane >> 4);
#pragma unroll
        for (int nt = 0; nt < 8; nt++) {
            int c = nt * 16 + l15;
#pragma unroll
            for (int r = 0; r < 4; r++) {
                lA[(w * 16 + m4 + r) * 128 + c] = f2bf(acc[nt][r]);
            }
        }
    }
    __syncthreads();

    // ---- epilogue: coalesced xp store + fused attention dots ----
    {
        const int r = tid >> 2;
        const long node = row_base + r;
        if (node < N_NODES) {
            const int h = tid & 3;
            const int c0 = h * 32;
            const uint4* s = (const uint4*)(lA + r * 128 + c0);
            uint4 v0 = s[0], v1 = s[1], v2 = s[2], v3 = s[3];
            uint4* d = (uint4*)(xp + node * HD + c0);
            d[0] = v0; d[1] = v1; d[2] = v2; d[3] = v3;
            // att dots over this head's 32 cols (values already in regs)
            const float* as = att_src + c0;
            const float* ad = att_dst + c0;
            float s0 = 0.f, s1 = 0.f;
            uint4 vv[4] = {v0, v1, v2, v3};
#pragma unroll
            for (int q = 0; q < 4; q++) {
                const uint* u = (const uint*)&vv[q];
#pragma unroll
                for (int p = 0; p < 4; p++) {
                    float f0 = __uint_as_float((u[p] & 0xffffu) << 16);
                    float f1 = __uint_as_float(u[p] & 0xffff0000u);
                    int cc = q * 8 + p * 2;
                    s0 = fmaf(f0, as[cc], s0);
                    s0 = fmaf(f1, as[cc + 1], s0);
                    s1 = fmaf(f0, ad[cc], s1);
                    s1 = fmaf(f1, ad[cc + 1], s1);
                }
            }
            asrc[node * HEADS + h] = s0;
            adst[node * HEADS + h] = s1;
        }
    }
}

// ---------------- K2: per-dst edge counts + within-segment rank (1 edge/thread) ----------------
// The atomic's return value IS the rank -> scatter needs no atomics.
__global__ void k_count(const int* __restrict__ ei, int* __restrict__ cnt,
                        int* __restrict__ rank) {
    int e = blockIdx.x * 256 + threadIdx.x;
    if (e < N_EDGES) rank[e] = atomicAdd(&cnt[ei[N_EDGES + e]], 1);
}

// ---------------- K3: exclusive scan of counts (3 kernels) ----------------
__global__ __launch_bounds__(256) void k_scan1(const int* __restrict__ cnt,
                                               int* __restrict__ row_start,
                                               int* __restrict__ partial) {
    __shared__ int lds[256];
    int t = threadIdx.x;
    int base = blockIdx.x * 1024 + t * 4;
    int c0 = (base + 0 < N_NODES) ? cnt[base + 0] : 0;
    int c1 = (base + 1 < N_NODES) ? cnt[base + 1] : 0;
    int c2 = (base + 2 < N_NODES) ? cnt[base + 2] : 0;
    int c3 = (base + 3 < N_NODES) ? cnt[base + 3] : 0;
    int p1 = c0, p2 = c0 + c1, p3 = c0 + c1 + c2;
    int tsum = p3 + c3;
    lds[t] = tsum;
    __syncthreads();
    for (int off = 1; off < 256; off <<= 1) {
        int v = (t >= off) ? lds[t - off] : 0;
        __syncthreads();
        lds[t] += v;
        __syncthreads();
    }
    int excl = (t == 0) ? 0 : lds[t - 1];
    if (base + 0 < N_NODES) row_start[base + 0] = excl;
    if (base + 1 < N_NODES) row_start[base + 1] = excl + p1;
    if (base + 2 < N_NODES) row_start[base + 2] = excl + p2;
    if (base + 3 < N_NODES) row_start[base + 3] = excl + p3;
    if (t == 255) partial[blockIdx.x] = lds[255];
}

__global__ __launch_bounds__(128) void k_scan2(int* __restrict__ partial) {
    __shared__ int lds[128];
    int t = threadIdx.x;
    int v = (t < SCAN_NBLK) ? partial[t] : 0;
    lds[t] = v;
    __syncthreads();
    for (int off = 1; off < 128; off <<= 1) {
        int u = (t >= off) ? lds[t - off] : 0;
        __syncthreads();
        lds[t] += u;
        __syncthreads();
    }
    if (t < SCAN_NBLK) partial[t] = (t == 0) ? 0 : lds[t - 1];
}

__global__ void k_scan3(int* __restrict__ row_start, const int* __restrict__ partial) {
    int i = blockIdx.x * 256 + threadIdx.x;
    if (i < N_NODES) row_start[i] = row_start[i] + partial[i >> 10];
    if (i == 0) row_start[N_NODES] = N_EDGES;
}

// ---------------- K4: atomic-free CSR scatter (1 edge/thread, dst-range pass) ----------------
// pos = row_start[d] + rank[e]; range-split so each pass's esrc write region (~3.2 MB)
// fits the 4 MB per-XCD L2.
__global__ void k_scatter(const int* __restrict__ ei,
                          const int* __restrict__ row_start,
                          const int* __restrict__ rank,
                          int* __restrict__ esrc,
                          int lo, int hi) {
    int e = blockIdx.x * 256 + threadIdx.x;
    if (e >= N_EDGES) return;
    int d = ei[N_EDGES + e];
    if (d < lo || d >= hi) return;
    esrc[row_start[d] + rank[e]] = ei[e];
}

// ---------------- K5: single-pass softmax + aggregation (1 wave/node) ----------------
// xp is bf16; lane owns output elements {2*lane, 2*lane+1} (head h=lane>>4), so each
// edge's row gather is ONE ushort2-per-lane load (256 B/wave = 1 row).
// Per 64-edge chunk: lane computes its edge's 4 head-weights in-register
// (leakyrelu(asrc4[src]+adst4[n]), unnormalized exp, clamp 80) and stages
// {weights, src} in per-wave LDS. Inner loop broadcasts via LDS reads
// (4-bank x 16-lane broadcast, conflict-free) instead of 5 shfls per edge.
__global__ __launch_bounds__(256) void k_aggregate(const int* __restrict__ row_start,
                                                   const int* __restrict__ esrc,
                                                   const float4* __restrict__ asrc4,
                                                   const float4* __restrict__ adst4,
                                                   const ushort* __restrict__ xp,
                                                   const float* __restrict__ bias,
                                                   float* __restrict__ out) {
    __shared__ float lw[4][64][4];  // [wave][edge][head] weights
    __shared__ int lsrc[4][64];     // [wave][edge] src ids
    const int wid = threadIdx.x >> 6;
    const int lane = threadIdx.x & 63;
    const int n = blockIdx.x * 4 + wid;
    if (n >= N_NODES) return;
    const int s0 = row_start[n];
    const int s1 = row_start[n + 1];
    const int h = lane >> 4;
    const float4 ad = adst4[n];  // wave-uniform

    float acc0 = 0.f, acc1 = 0.f, den = 0.f;

    for (int base = s0; base < s1; base += 64) {
        const int rem = s1 - base;
        const int cnt = rem < 64 ? rem : 64;
        const bool v = lane < cnt;
        int msrc = v ? esrc[base + lane] : 0;
        float4 as = asrc4[msrc];
        float tx = as.x + ad.x, ty = as.y + ad.y, tz = as.z + ad.z, tw = as.w + ad.w;
        tx = (tx >= 0.f) ? tx : NEG_SLOPE * tx;
        ty = (ty >= 0.f) ? ty : NEG_SLOPE * ty;
        tz = (tz >= 0.f) ? tz : NEG_SLOPE * tz;
        tw = (tw >= 0.f) ? tw : NEG_SLOPE * tw;
        float4 wv;
        wv.x = v ? __expf(fminf(tx, 80.f)) : 0.f;
        wv.y = v ? __expf(fminf(ty, 80.f)) : 0.f;
        wv.z = v ? __expf(fminf(tz, 80.f)) : 0.f;
        wv.w = v ? __expf(fminf(tw, 80.f)) : 0.f;
        lsrc[wid][lane] = msrc;
        *(float4*)&lw[wid][lane][0] = wv;
        // wave-internal LDS staging: in-lockstep wave, compiler orders ds ops (lgkmcnt)

        int j = 0;
        for (; j + 4 <= cnt; j += 4) {
            float e0 = lw[wid][j + 0][h];
            float e1 = lw[wid][j + 1][h];
            float e2 = lw[wid][j + 2][h];
            float e3 = lw[wid][j + 3][h];
            int4 sv = *(const int4*)&lsrc[wid][j];  // uniform broadcast
            const uint* p0 = (const uint*)(xp + (long)sv.x * HD) + lane;
            const uint* p1 = (const uint*)(xp + (long)sv.y * HD) + lane;
            const uint* p2 = (const uint*)(xp + (long)sv.z * HD) + lane;
            const uint* p3 = (const uint*)(xp + (long)sv.w * HD) + lane;
            uint g0 = *p0, g1 = *p1, g2 = *p2, g3 = *p3;
            den += (e0 + e1) + (e2 + e3);
            acc0 = fmaf(e0, __uint_as_float((g0 & 0xffffu) << 16), acc0);
            acc1 = fmaf(e0, __uint_as_float(g0 & 0xffff0000u), acc1);
            acc0 = fmaf(e1, __uint_as_float((g1 & 0xffffu) << 16), acc0);
            acc1 = fmaf(e1, __uint_as_float(g1 & 0xffff0000u), acc1);
            acc0 = fmaf(e2, __uint_as_float((g2 & 0xffffu) << 16), acc0);
            acc1 = fmaf(e2, __uint_as_float(g2 & 0xffff0000u), acc1);
            acc0 = fmaf(e3, __uint_as_float((g3 & 0xffffu) << 16), acc0);
            acc1 = fmaf(e3, __uint_as_float(g3 & 0xffff0000u), acc1);
        }
        for (; j < cnt; j++) {
            float e = lw[wid][j][h];
            int src = lsrc[wid][j];
            uint g = *((const uint*)(xp + (long)src * HD) + lane);
            den += e;
            acc0 = fmaf(e, __uint_as_float((g & 0xffffu) << 16), acc0);
            acc1 = fmaf(e, __uint_as_float(g & 0xffff0000u), acc1);
        }
    }
    float inv = 1.f / (den + 1e-12f);
    float2 b2 = ((const float2*)bias)[lane];
    float2 o;
    o.x = acc0 * inv + b2.x;
    o.y = acc1 * inv + b2.y;
    ((float2*)(out + (long)n * HD))[lane] = o;
}

extern "C" void kernel_launch(void* const* d_in, const int* in_sizes, int n_in,
                              void* d_out, int out_size, void* d_ws, size_t ws_size,
                              hipStream_t stream) {
    const float* x = (const float*)d_in[0];
    const int* ei = (const int*)d_in[1];
    const float* W = (const float*)d_in[2];
    const float* att_src = (const float*)d_in[3];
    const float* att_dst = (const float*)d_in[4];
    const float* bias = (const float*)d_in[5];
    float* out = (float*)d_out;
    char* ws = (char*)d_ws;

    // workspace layout (bytes), 16B-aligned
    ushort* xp       = (ushort*)(ws + 0);         // 25,600,000 (bf16 x_proj)
    float* asrc      = (float*)(ws + 25600000);   //  1,600,000
    float* adst      = (float*)(ws + 27200000);   //  1,600,000
    int* esrc        = (int*)(ws + 28800000);     //  6,400,000
    int* rank        = (int*)(ws + 35200000);     //  6,400,000
    int* cnt         = (int*)(ws + 41600000);     //    400,000
    int* row_start   = (int*)(ws + 42000000);     //    400,004
    int* partial     = (int*)(ws + 42400016);     //        512
    // total ~42.4 MB

    hipMemsetAsync(cnt, 0, N_NODES * sizeof(int), stream);
    k_gemm<<<(N_NODES + 63) / 64, 256, 0, stream>>>(x, W, xp, att_src, att_dst, asrc, adst);
    k_count<<<(N_EDGES + 255) / 256, 256, 0, stream>>>(ei, cnt, rank);
    k_scan1<<<SCAN_NBLK, 256, 0, stream>>>(cnt, row_start, partial);
    k_scan2<<<1, 128, 0, stream>>>(partial);
    k_scan3<<<(N_NODES + 255) / 256, 256, 0, stream>>>(row_start, partial);
    k_scatter<<<(N_EDGES + 255) / 256, 256, 0, stream>>>(ei, row_start, rank, esrc, 0, N_NODES / 2);
    k_scatter<<<(N_EDGES + 255) / 256, 256, 0, stream>>>(ei, row_start, rank, esrc, N_NODES / 2, N_NODES);
    k_aggregate<<<(N_NODES + 3) / 4, 256, 0, stream>>>(row_start, esrc,
                                                       (const float4*)asrc, (const float4*)adst,
                                                       xp, bias, out);
}

// Round 7
// 222.089 us; speedup vs baseline: 1.5728x; 1.0282x over previous
//
#include <hip/hip_runtime.h>
#include <math.h>

#define N_NODES 100000
#define N_EDGES 1600000
#define IN_DIM 128
#define HEADS 4
#define OUT_DIM 32
#define HD 128  // HEADS*OUT_DIM
#define NEG_SLOPE 0.2f
#define SCAN_NBLK 98  // ceil(100000/1024)

typedef __attribute__((ext_vector_type(8))) short short8;
typedef __attribute__((ext_vector_type(4))) float f32x4;

__device__ inline ushort f2bf(float f) {
    // round-to-nearest-even fp32 -> bf16
    uint u = __float_as_uint(f);
    u += 0x7fffu + ((u >> 16) & 1u);
    return (ushort)(u >> 16);
}

// ---------------- K1: x_proj = x @ W^T  (bf16 MFMA, fused att-dots) ----------------
// Block: 256 threads (4 waves). Tile: 64 rows x 128 cols, K=128.
// LDS: lA = 64x128 bf16 A-tile (reused as out-tile), lB = 128x128 bf16 W-tile.
// Both XOR-swizzled (byte ^= (row&7)<<4) so ds_read_b128 fragments are ~conflict-free.
__global__ __launch_bounds__(256) void k_gemm(const float* __restrict__ x,
                                              const float* __restrict__ W,
                                              ushort* __restrict__ xp,
                                              const float* __restrict__ att_src,
                                              const float* __restrict__ att_dst,
                                              float* __restrict__ asrc,
                                              float* __restrict__ adst) {
    __shared__ ushort lA[64 * 128];   // 16 KB
    __shared__ ushort lB[128 * 128];  // 32 KB
    const int tid = threadIdx.x;
    const long row_base = (long)blockIdx.x * 64;

    // ---- stage A (x rows, fp32 -> bf16, swizzled) ----
    {
        const int r = tid >> 2;
        const int c0 = (tid & 3) * 32;
        const long row = row_base + r;
        const float* src = x + row * IN_DIM + c0;
#pragma unroll
        for (int i = 0; i < 4; i++) {  // 8 cols per iter
            float4 va, vb;
            if (row < N_NODES) {
                va = *(const float4*)(src + 8 * i);
                vb = *(const float4*)(src + 8 * i + 4);
            } else {
                va = make_float4(0.f, 0.f, 0.f, 0.f);
                vb = va;
            }
            ushort h[8] = {f2bf(va.x), f2bf(va.y), f2bf(va.z), f2bf(va.w),
                           f2bf(vb.x), f2bf(vb.y), f2bf(vb.z), f2bf(vb.w)};
            uint byte = (uint)(r * 256 + (c0 + 8 * i) * 2);
            byte ^= (uint)((r & 7) << 4);
            *(uint4*)((char*)lA + byte) = *(const uint4*)h;
        }
    }
    // ---- stage B (W rows, fp32 -> bf16, swizzled): lB[c][k] = W[c][k] ----
    {
        const int c = tid >> 1;
        const int k0 = (tid & 1) * 64;
        const float* src = W + c * IN_DIM + k0;
#pragma unroll
        for (int i = 0; i < 8; i++) {  // 8 k per iter
            float4 va = *(const float4*)(src + 8 * i);
            float4 vb = *(const float4*)(src + 8 * i + 4);
            ushort h[8] = {f2bf(va.x), f2bf(va.y), f2bf(va.z), f2bf(va.w),
                           f2bf(vb.x), f2bf(vb.y), f2bf(vb.z), f2bf(vb.w)};
            uint byte = (uint)(c * 256 + (k0 + 8 * i) * 2);
            byte ^= (uint)((c & 7) << 4);
            *(uint4*)((char*)lB + byte) = *(const uint4*)h;
        }
    }
    __syncthreads();

    // ---- MFMA main: wave w owns rows w*16..w*16+15, all 128 cols ----
    const int w = tid >> 6;
    const int lane = tid & 63;
    const int l15 = lane & 15;
    const int g8 = (lane >> 4) * 8;  // k sub-offset (consistent convention for A and B)
    const int arow = w * 16 + l15;

    f32x4 acc[8];
#pragma unroll
    for (int nt = 0; nt < 8; nt++) acc[nt] = (f32x4){0.f, 0.f, 0.f, 0.f};

#pragma unroll
    for (int t = 0; t < 4; t++) {
        uint ab = (uint)(arow * 256 + (t * 32 + g8) * 2);
        ab ^= (uint)((arow & 7) << 4);
        short8 af = *(const short8*)((const char*)lA + ab);
#pragma unroll
        for (int nt = 0; nt < 8; nt++) {
            int c = nt * 16 + l15;
            uint bb = (uint)(c * 256 + (t * 32 + g8) * 2);
            bb ^= (uint)((c & 7) << 4);
            short8 bfr = *(const short8*)((const char*)lB + bb);
            acc[nt] = __builtin_amdgcn_mfma_f32_16x16x32_bf16(af, bfr, acc[nt], 0, 0, 0);
        }
    }
    __syncthreads();  // done reading lA/lB; reuse lA as out-tile

    // ---- write acc -> lA (linear [64][128] bf16 out-tile) ----
    // C/D layout: col = lane&15, row = 4*(lane>>4)+reg  [m89/m91]
    {
        const int m4 = 4 * (lane >> 4);
#pragma unroll
        for (int nt = 0; nt < 8; nt++) {
            int c = nt * 16 + l15;
#pragma unroll
            for (int r = 0; r < 4; r++) {
                lA[(w * 16 + m4 + r) * 128 + c] = f2bf(acc[nt][r]);
            }
        }
    }
    __syncthreads();

    // ---- epilogue: coalesced xp store + fused attention dots ----
    {
        const int r = tid >> 2;
        const long node = row_base + r;
        if (node < N_NODES) {
            const int h = tid & 3;
            const int c0 = h * 32;
            const uint4* s = (const uint4*)(lA + r * 128 + c0);
            uint4 v0 = s[0], v1 = s[1], v2 = s[2], v3 = s[3];
            uint4* d = (uint4*)(xp + node * HD + c0);
            d[0] = v0; d[1] = v1; d[2] = v2; d[3] = v3;
            // att dots over this head's 32 cols (values already in regs)
            const float* as = att_src + c0;
            const float* ad = att_dst + c0;
            float s0 = 0.f, s1 = 0.f;
            uint4 vv[4] = {v0, v1, v2, v3};
#pragma unroll
            for (int q = 0; q < 4; q++) {
                const uint* u = (const uint*)&vv[q];
#pragma unroll
                for (int p = 0; p < 4; p++) {
                    float f0 = __uint_as_float((u[p] & 0xffffu) << 16);
                    float f1 = __uint_as_float(u[p] & 0xffff0000u);
                    int cc = q * 8 + p * 2;
                    s0 = fmaf(f0, as[cc], s0);
                    s0 = fmaf(f1, as[cc + 1], s0);
                    s1 = fmaf(f0, ad[cc], s1);
                    s1 = fmaf(f1, ad[cc + 1], s1);
                }
            }
            asrc[node * HEADS + h] = s0;
            adst[node * HEADS + h] = s1;
        }
    }
}

// ---------------- K2: per-dst edge counts + within-segment rank (1 edge/thread) ----------------
// The atomic's return value IS the rank -> scatter needs no atomics.
__global__ void k_count(const int* __restrict__ ei, int* __restrict__ cnt,
                        int* __restrict__ rank) {
    int e = blockIdx.x * 256 + threadIdx.x;
    if (e < N_EDGES) rank[e] = atomicAdd(&cnt[ei[N_EDGES + e]], 1);
}

// ---------------- K3: exclusive scan of counts (3 kernels) ----------------
__global__ __launch_bounds__(256) void k_scan1(const int* __restrict__ cnt,
                                               int* __restrict__ row_start,
                                               int* __restrict__ partial) {
    __shared__ int lds[256];
    int t = threadIdx.x;
    int base = blockIdx.x * 1024 + t * 4;
    int c0 = (base + 0 < N_NODES) ? cnt[base + 0] : 0;
    int c1 = (base + 1 < N_NODES) ? cnt[base + 1] : 0;
    int c2 = (base + 2 < N_NODES) ? cnt[base + 2] : 0;
    int c3 = (base + 3 < N_NODES) ? cnt[base + 3] : 0;
    int p1 = c0, p2 = c0 + c1, p3 = c0 + c1 + c2;
    int tsum = p3 + c3;
    lds[t] = tsum;
    __syncthreads();
    for (int off = 1; off < 256; off <<= 1) {
        int v = (t >= off) ? lds[t - off] : 0;
        __syncthreads();
        lds[t] += v;
        __syncthreads();
    }
    int excl = (t == 0) ? 0 : lds[t - 1];
    if (base + 0 < N_NODES) row_start[base + 0] = excl;
    if (base + 1 < N_NODES) row_start[base + 1] = excl + p1;
    if (base + 2 < N_NODES) row_start[base + 2] = excl + p2;
    if (base + 3 < N_NODES) row_start[base + 3] = excl + p3;
    if (t == 255) partial[blockIdx.x] = lds[255];
}

__global__ __launch_bounds__(128) void k_scan2(int* __restrict__ partial) {
    __shared__ int lds[128];
    int t = threadIdx.x;
    int v = (t < SCAN_NBLK) ? partial[t] : 0;
    lds[t] = v;
    __syncthreads();
    for (int off = 1; off < 128; off <<= 1) {
        int u = (t >= off) ? lds[t - off] : 0;
        __syncthreads();
        lds[t] += u;
        __syncthreads();
    }
    if (t < SCAN_NBLK) partial[t] = (t == 0) ? 0 : lds[t - 1];
}

__global__ void k_scan3(int* __restrict__ row_start, const int* __restrict__ partial) {
    int i = blockIdx.x * 256 + threadIdx.x;
    if (i < N_NODES) row_start[i] = row_start[i] + partial[i >> 10];
    if (i == 0) row_start[N_NODES] = N_EDGES;
}

// ---------------- K4: atomic-free CSR scatter, single pass ----------------
// esrc stores PRE-SHIFTED byte offsets (src*256 = src row offset in bf16 xp),
// so aggregate's per-edge address math is a single 32-bit add.
__global__ void k_scatter(const int* __restrict__ ei,
                          const int* __restrict__ row_start,
                          const int* __restrict__ rank,
                          int* __restrict__ esrc) {
    int e = blockIdx.x * 256 + threadIdx.x;
    if (e >= N_EDGES) return;
    int d = ei[N_EDGES + e];
    esrc[row_start[d] + rank[e]] = ei[e] << 8;
}

// ---------------- K5: single-pass softmax + aggregation (1 wave/node) ----------------
// xp is bf16; lane owns output elements {2*lane, 2*lane+1} (head h=lane>>4): each
// edge's row gather is ONE dword-per-lane saddr load (256 B/wave = 1 row).
// Per 64-edge chunk: every lane stages {4 head-weights, byte-offset} in per-wave LDS
// (invalid lanes stage weight 0, offset 0 -> contribute nothing), so the inner loop
// runs 8-wide with NO tail: 8 gathers in flight, ~7 VALU/edge.
__global__ __launch_bounds__(256) void k_aggregate(const int* __restrict__ row_start,
                                                   const int* __restrict__ esrc,
                                                   const char* __restrict__ asrcB,
                                                   const float4* __restrict__ adst4,
                                                   const char* __restrict__ xpB,
                                                   const float* __restrict__ bias,
                                                   float* __restrict__ out) {
    __shared__ float lw[4][64][4];  // [wave][edge][head] weights
    __shared__ int loff[4][64];     // [wave][edge] xp byte offsets
    const int wid = threadIdx.x >> 6;
    const int lane = threadIdx.x & 63;
    const int n = blockIdx.x * 4 + wid;
    if (n >= N_NODES) return;
    const int s0 = row_start[n];
    const int s1 = row_start[n + 1];
    const int h = lane >> 4;
    const uint lane4 = (uint)lane * 4;
    const float4 ad = adst4[n];  // wave-uniform

    float acc0 = 0.f, acc1 = 0.f, den = 0.f;

    for (int base = s0; base < s1; base += 64) {
        const int rem = s1 - base;
        const int cnt = rem < 64 ? rem : 64;
        const bool v = lane < cnt;
        int moff = v ? esrc[base + lane] : 0;  // src*256 (byte offset)
        float4 as = *(const float4*)(asrcB + (moff >> 4));  // src*16
        float tx = as.x + ad.x, ty = as.y + ad.y, tz = as.z + ad.z, tw = as.w + ad.w;
        tx = (tx >= 0.f) ? tx : NEG_SLOPE * tx;
        ty = (ty >= 0.f) ? ty : NEG_SLOPE * ty;
        tz = (tz >= 0.f) ? tz : NEG_SLOPE * tz;
        tw = (tw >= 0.f) ? tw : NEG_SLOPE * tw;
        float4 wv;
        wv.x = v ? __expf(fminf(tx, 80.f)) : 0.f;
        wv.y = v ? __expf(fminf(ty, 80.f)) : 0.f;
        wv.z = v ? __expf(fminf(tz, 80.f)) : 0.f;
        wv.w = v ? __expf(fminf(tw, 80.f)) : 0.f;
        loff[wid][lane] = moff;
        *(float4*)&lw[wid][lane][0] = wv;
        // same-wave LDS staging: compiler inserts lgkmcnt ordering

        const int cnt8 = (cnt + 7) & ~7;  // padded: dummy edges have weight 0
        for (int j = 0; j < cnt8; j += 8) {
            float e0 = lw[wid][j + 0][h], e1 = lw[wid][j + 1][h];
            float e2 = lw[wid][j + 2][h], e3 = lw[wid][j + 3][h];
            float e4 = lw[wid][j + 4][h], e5 = lw[wid][j + 5][h];
            float e6 = lw[wid][j + 6][h], e7 = lw[wid][j + 7][h];
            int4 sv0 = *(const int4*)&loff[wid][j];      // uniform broadcast
            int4 sv1 = *(const int4*)&loff[wid][j + 4];
            uint g0 = *(const uint*)(xpB + ((uint)sv0.x + lane4));
            uint g1 = *(const uint*)(xpB + ((uint)sv0.y + lane4));
            uint g2 = *(const uint*)(xpB + ((uint)sv0.z + lane4));
            uint g3 = *(const uint*)(xpB + ((uint)sv0.w + lane4));
            uint g4 = *(const uint*)(xpB + ((uint)sv1.x + lane4));
            uint g5 = *(const uint*)(xpB + ((uint)sv1.y + lane4));
            uint g6 = *(const uint*)(xpB + ((uint)sv1.z + lane4));
            uint g7 = *(const uint*)(xpB + ((uint)sv1.w + lane4));
            den += ((e0 + e1) + (e2 + e3)) + ((e4 + e5) + (e6 + e7));
            acc0 = fmaf(e0, __uint_as_float(g0 << 16), acc0);
            acc1 = fmaf(e0, __uint_as_float(g0 & 0xffff0000u), acc1);
            acc0 = fmaf(e1, __uint_as_float(g1 << 16), acc0);
            acc1 = fmaf(e1, __uint_as_float(g1 & 0xffff0000u), acc1);
            acc0 = fmaf(e2, __uint_as_float(g2 << 16), acc0);
            acc1 = fmaf(e2, __uint_as_float(g2 & 0xffff0000u), acc1);
            acc0 = fmaf(e3, __uint_as_float(g3 << 16), acc0);
            acc1 = fmaf(e3, __uint_as_float(g3 & 0xffff0000u), acc1);
            acc0 = fmaf(e4, __uint_as_float(g4 << 16), acc0);
            acc1 = fmaf(e4, __uint_as_float(g4 & 0xffff0000u), acc1);
            acc0 = fmaf(e5, __uint_as_float(g5 << 16), acc0);
            acc1 = fmaf(e5, __uint_as_float(g5 & 0xffff0000u), acc1);
            acc0 = fmaf(e6, __uint_as_float(g6 << 16), acc0);
            acc1 = fmaf(e6, __uint_as_float(g6 & 0xffff0000u), acc1);
            acc0 = fmaf(e7, __uint_as_float(g7 << 16), acc0);
            acc1 = fmaf(e7, __uint_as_float(g7 & 0xffff0000u), acc1);
        }
    }
    float inv = 1.f / (den + 1e-12f);
    float2 b2 = ((const float2*)bias)[lane];
    float2 o;
    o.x = acc0 * inv + b2.x;
    o.y = acc1 * inv + b2.y;
    ((float2*)(out + (long)n * HD))[lane] = o;
}

extern "C" void kernel_launch(void* const* d_in, const int* in_sizes, int n_in,
                              void* d_out, int out_size, void* d_ws, size_t ws_size,
                              hipStream_t stream) {
    const float* x = (const float*)d_in[0];
    const int* ei = (const int*)d_in[1];
    const float* W = (const float*)d_in[2];
    const float* att_src = (const float*)d_in[3];
    const float* att_dst = (const float*)d_in[4];
    const float* bias = (const float*)d_in[5];
    float* out = (float*)d_out;
    char* ws = (char*)d_ws;

    // workspace layout (bytes), 16B-aligned
    ushort* xp       = (ushort*)(ws + 0);         // 25,600,000 (bf16 x_proj)
    float* asrc      = (float*)(ws + 25600000);   //  1,600,000
    float* adst      = (float*)(ws + 27200000);   //  1,600,000
    int* esrc        = (int*)(ws + 28800000);     //  6,400,000
    int* rank        = (int*)(ws + 35200000);     //  6,400,000
    int* cnt         = (int*)(ws + 41600000);     //    400,000
    int* row_start   = (int*)(ws + 42000000);     //    400,004
    int* partial     = (int*)(ws + 42400016);     //        512
    // total ~42.4 MB

    hipMemsetAsync(cnt, 0, N_NODES * sizeof(int), stream);
    k_gemm<<<(N_NODES + 63) / 64, 256, 0, stream>>>(x, W, xp, att_src, att_dst, asrc, adst);
    k_count<<<(N_EDGES + 255) / 256, 256, 0, stream>>>(ei, cnt, rank);
    k_scan1<<<SCAN_NBLK, 256, 0, stream>>>(cnt, row_start, partial);
    k_scan2<<<1, 128, 0, stream>>>(partial);
    k_scan3<<<(N_NODES + 255) / 256, 256, 0, stream>>>(row_start, partial);
    k_scatter<<<(N_EDGES + 255) / 256, 256, 0, stream>>>(ei, row_start, rank, esrc);
    k_aggregate<<<(N_NODES + 3) / 4, 256, 0, stream>>>(row_start, esrc,
                                                       (const char*)asrc, (const float4*)adst,
                                                       (const char*)xp, bias, out);
}

// Round 8
// 206.688 us; speedup vs baseline: 1.6900x; 1.0745x over previous
//
#include <hip/hip_runtime.h>
#include <math.h>

#define N_NODES 100000
#define N_EDGES 1600000
#define IN_DIM 128
#define HEADS 4
#define OUT_DIM 32
#define HD 128  // HEADS*OUT_DIM
#define NEG_SLOPE 0.2f
#define SCAN_NBLK 98    // ceil(100000/1024)
#define GEMM_BLKS 1563  // ceil(100000/64)
#define COUNT_BLKS 6250 // ceil(1600000/256)

typedef __attribute__((ext_vector_type(8))) short short8;
typedef __attribute__((ext_vector_type(4))) float f32x4;

__device__ inline ushort f2bf(float f) {
    // round-to-nearest-even fp32 -> bf16
    uint u = __float_as_uint(f);
    u += 0x7fffu + ((u >> 16) & 1u);
    return (ushort)(u >> 16);
}

// ---------------- K1: grid-partitioned fusion: [gemm blocks | count blocks] ----------------
// gemm: x_proj = x @ W^T (bf16 MFMA, fused att-dots), 64 rows/block.
// count: per-dst histogram + within-segment rank (atomic return value IS the rank).
// The two are independent; fusing lets count's atomic latency hide under gemm's MFMA.
__global__ __launch_bounds__(256) void k_gemm_count(const float* __restrict__ x,
                                                    const float* __restrict__ W,
                                                    ushort* __restrict__ xp,
                                                    const float* __restrict__ att_src,
                                                    const float* __restrict__ att_dst,
                                                    float* __restrict__ asrc,
                                                    float* __restrict__ adst,
                                                    const int* __restrict__ ei,
                                                    int* __restrict__ cnt,
                                                    int* __restrict__ rank) {
    __shared__ ushort lA[64 * 128];   // 16 KB
    __shared__ ushort lB[128 * 128];  // 32 KB

    if (blockIdx.x >= GEMM_BLKS) {
        // ---------- count path ----------
        int e = (blockIdx.x - GEMM_BLKS) * 256 + threadIdx.x;
        if (e < N_EDGES) rank[e] = atomicAdd(&cnt[ei[N_EDGES + e]], 1);
        return;
    }

    // ---------- gemm path ----------
    const int tid = threadIdx.x;
    const long row_base = (long)blockIdx.x * 64;

    // ---- stage A (x rows, fp32 -> bf16, swizzled) ----
    {
        const int r = tid >> 2;
        const int c0 = (tid & 3) * 32;
        const long row = row_base + r;
        const float* src = x + row * IN_DIM + c0;
#pragma unroll
        for (int i = 0; i < 4; i++) {  // 8 cols per iter
            float4 va, vb;
            if (row < N_NODES) {
                va = *(const float4*)(src + 8 * i);
                vb = *(const float4*)(src + 8 * i + 4);
            } else {
                va = make_float4(0.f, 0.f, 0.f, 0.f);
                vb = va;
            }
            ushort h[8] = {f2bf(va.x), f2bf(va.y), f2bf(va.z), f2bf(va.w),
                           f2bf(vb.x), f2bf(vb.y), f2bf(vb.z), f2bf(vb.w)};
            uint byte = (uint)(r * 256 + (c0 + 8 * i) * 2);
            byte ^= (uint)((r & 7) << 4);
            *(uint4*)((char*)lA + byte) = *(const uint4*)h;
        }
    }
    // ---- stage B (W rows, fp32 -> bf16, swizzled): lB[c][k] = W[c][k] ----
    {
        const int c = tid >> 1;
        const int k0 = (tid & 1) * 64;
        const float* src = W + c * IN_DIM + k0;
#pragma unroll
        for (int i = 0; i < 8; i++) {  // 8 k per iter
            float4 va = *(const float4*)(src + 8 * i);
            float4 vb = *(const float4*)(src + 8 * i + 4);
            ushort h[8] = {f2bf(va.x), f2bf(va.y), f2bf(va.z), f2bf(va.w),
                           f2bf(vb.x), f2bf(vb.y), f2bf(vb.z), f2bf(vb.w)};
            uint byte = (uint)(c * 256 + (k0 + 8 * i) * 2);
            byte ^= (uint)((c & 7) << 4);
            *(uint4*)((char*)lB + byte) = *(const uint4*)h;
        }
    }
    __syncthreads();

    // ---- MFMA main: wave w owns rows w*16..w*16+15, all 128 cols ----
    const int w = tid >> 6;
    const int lane = tid & 63;
    const int l15 = lane & 15;
    const int g8 = (lane >> 4) * 8;  // k sub-offset (consistent convention for A and B)
    const int arow = w * 16 + l15;

    f32x4 acc[8];
#pragma unroll
    for (int nt = 0; nt < 8; nt++) acc[nt] = (f32x4){0.f, 0.f, 0.f, 0.f};

#pragma unroll
    for (int t = 0; t < 4; t++) {
        uint ab = (uint)(arow * 256 + (t * 32 + g8) * 2);
        ab ^= (uint)((arow & 7) << 4);
        short8 af = *(const short8*)((const char*)lA + ab);
#pragma unroll
        for (int nt = 0; nt < 8; nt++) {
            int c = nt * 16 + l15;
            uint bb = (uint)(c * 256 + (t * 32 + g8) * 2);
            bb ^= (uint)((c & 7) << 4);
            short8 bfr = *(const short8*)((const char*)lB + bb);
            acc[nt] = __builtin_amdgcn_mfma_f32_16x16x32_bf16(af, bfr, acc[nt], 0, 0, 0);
        }
    }
    __syncthreads();  // done reading lA/lB; reuse lA as out-tile

    // ---- write acc -> lA (linear [64][128] bf16 out-tile) ----
    // C/D layout: col = lane&15, row = 4*(lane>>4)+reg  [m89/m91]
    {
        const int m4 = 4 * (lane >> 4);
#pragma unroll
        for (int nt = 0; nt < 8; nt++) {
            int c = nt * 16 + l15;
#pragma unroll
            for (int r = 0; r < 4; r++) {
                lA[(w * 16 + m4 + r) * 128 + c] = f2bf(acc[nt][r]);
            }
        }
    }
    __syncthreads();

    // ---- epilogue: coalesced xp store + fused attention dots ----
    {
        const int r = tid >> 2;
        const long node = row_base + r;
        if (node < N_NODES) {
            const int h = tid & 3;
            const int c0 = h * 32;
            const uint4* s = (const uint4*)(lA + r * 128 + c0);
            uint4 v0 = s[0], v1 = s[1], v2 = s[2], v3 = s[3];
            uint4* d = (uint4*)(xp + node * HD + c0);
            d[0] = v0; d[1] = v1; d[2] = v2; d[3] = v3;
            // att dots over this head's 32 cols (values already in regs)
            const float* as = att_src + c0;
            const float* ad = att_dst + c0;
            float s0 = 0.f, s1 = 0.f;
            uint4 vv[4] = {v0, v1, v2, v3};
#pragma unroll
            for (int q = 0; q < 4; q++) {
                const uint* u = (const uint*)&vv[q];
#pragma unroll
                for (int p = 0; p < 4; p++) {
                    float f0 = __uint_as_float((u[p] & 0xffffu) << 16);
                    float f1 = __uint_as_float(u[p] & 0xffff0000u);
                    int cc = q * 8 + p * 2;
                    s0 = fmaf(f0, as[cc], s0);
                    s0 = fmaf(f1, as[cc + 1], s0);
                    s1 = fmaf(f0, ad[cc], s1);
                    s1 = fmaf(f1, ad[cc + 1], s1);
                }
            }
            asrc[node * HEADS + h] = s0;
            adst[node * HEADS + h] = s1;
        }
    }
}

// ---------------- K3a: block-level exclusive scan of counts ----------------
__global__ __launch_bounds__(256) void k_scan1(const int* __restrict__ cnt,
                                               int* __restrict__ row_start,
                                               int* __restrict__ partial) {
    __shared__ int lds[256];
    int t = threadIdx.x;
    int base = blockIdx.x * 1024 + t * 4;
    int c0 = (base + 0 < N_NODES) ? cnt[base + 0] : 0;
    int c1 = (base + 1 < N_NODES) ? cnt[base + 1] : 0;
    int c2 = (base + 2 < N_NODES) ? cnt[base + 2] : 0;
    int c3 = (base + 3 < N_NODES) ? cnt[base + 3] : 0;
    int p1 = c0, p2 = c0 + c1, p3 = c0 + c1 + c2;
    int tsum = p3 + c3;
    lds[t] = tsum;
    __syncthreads();
    for (int off = 1; off < 256; off <<= 1) {
        int v = (t >= off) ? lds[t - off] : 0;
        __syncthreads();
        lds[t] += v;
        __syncthreads();
    }
    int excl = (t == 0) ? 0 : lds[t - 1];
    if (base + 0 < N_NODES) row_start[base + 0] = excl;
    if (base + 1 < N_NODES) row_start[base + 1] = excl + p1;
    if (base + 2 < N_NODES) row_start[base + 2] = excl + p2;
    if (base + 3 < N_NODES) row_start[base + 3] = excl + p3;
    if (t == 255) partial[blockIdx.x] = lds[255];
}

// ---------------- K3b: apply block prefixes (scan of <=98 partials done in-block) ----------------
__global__ __launch_bounds__(256) void k_scan3(int* __restrict__ row_start,
                                               const int* __restrict__ partial) {
    __shared__ int sprefix;
    const int b = blockIdx.x;
    const int g = b >> 2;  // 1024-node group; uniform per 256-node block
    const int t = threadIdx.x;
    if (t < 64) {
        int p = (t < g) ? partial[t] : 0;
        if (t + 64 < g) p += partial[t + 64];
#pragma unroll
        for (int off = 32; off > 0; off >>= 1) p += __shfl_down(p, off);
        if (t == 0) sprefix = p;
    }
    __syncthreads();
    int i = b * 256 + t;
    if (i < N_NODES) row_start[i] += sprefix;
    if (i == 0) row_start[N_NODES] = N_EDGES;
}

// ---------------- K4: atomic-free CSR scatter, single pass ----------------
// esrc stores PRE-SHIFTED byte offsets (src*256 = src row offset in bf16 xp),
// so aggregate's per-edge address math is a single 32-bit add.
__global__ void k_scatter(const int* __restrict__ ei,
                          const int* __restrict__ row_start,
                          const int* __restrict__ rank,
                          int* __restrict__ esrc) {
    int e = blockIdx.x * 256 + threadIdx.x;
    if (e >= N_EDGES) return;
    int d = ei[N_EDGES + e];
    esrc[row_start[d] + rank[e]] = ei[e] << 8;
}

// ---------------- K5: single-pass softmax + aggregation (1 wave/node) ----------------
// xp is bf16; lane owns output elements {2*lane, 2*lane+1} (head h=lane>>4): each
// edge's row gather is ONE dword-per-lane saddr load (256 B/wave = 1 row).
// Per 64-edge chunk: every lane stages {4 head-weights, byte-offset} in per-wave LDS
// (invalid lanes stage weight 0, offset 0 -> contribute nothing), so the inner loop
// runs 8-wide with NO tail: 8 gathers in flight, ~7 VALU/edge.
__global__ __launch_bounds__(256) void k_aggregate(const int* __restrict__ row_start,
                                                   const int* __restrict__ esrc,
                                                   const char* __restrict__ asrcB,
                                                   const float4* __restrict__ adst4,
                                                   const char* __restrict__ xpB,
                                                   const float* __restrict__ bias,
                                                   float* __restrict__ out) {
    __shared__ float lw[4][64][4];  // [wave][edge][head] weights
    __shared__ int loff[4][64];     // [wave][edge] xp byte offsets
    const int wid = threadIdx.x >> 6;
    const int lane = threadIdx.x & 63;
    const int n = blockIdx.x * 4 + wid;
    if (n >= N_NODES) return;
    const int s0 = row_start[n];
    const int s1 = row_start[n + 1];
    const int h = lane >> 4;
    const uint lane4 = (uint)lane * 4;
    const float4 ad = adst4[n];  // wave-uniform

    float acc0 = 0.f, acc1 = 0.f, den = 0.f;

    for (int base = s0; base < s1; base += 64) {
        const int rem = s1 - base;
        const int cnt = rem < 64 ? rem : 64;
        const bool v = lane < cnt;
        int moff = v ? esrc[base + lane] : 0;  // src*256 (byte offset)
        float4 as = *(const float4*)(asrcB + (moff >> 4));  // src*16
        float tx = as.x + ad.x, ty = as.y + ad.y, tz = as.z + ad.z, tw = as.w + ad.w;
        tx = (tx >= 0.f) ? tx : NEG_SLOPE * tx;
        ty = (ty >= 0.f) ? ty : NEG_SLOPE * ty;
        tz = (tz >= 0.f) ? tz : NEG_SLOPE * tz;
        tw = (tw >= 0.f) ? tw : NEG_SLOPE * tw;
        float4 wv;
        wv.x = v ? __expf(fminf(tx, 80.f)) : 0.f;
        wv.y = v ? __expf(fminf(ty, 80.f)) : 0.f;
        wv.z = v ? __expf(fminf(tz, 80.f)) : 0.f;
        wv.w = v ? __expf(fminf(tw, 80.f)) : 0.f;
        loff[wid][lane] = moff;
        *(float4*)&lw[wid][lane][0] = wv;
        // same-wave LDS staging: compiler inserts lgkmcnt ordering

        const int cnt8 = (cnt + 7) & ~7;  // padded: dummy edges have weight 0
        for (int j = 0; j < cnt8; j += 8) {
            float e0 = lw[wid][j + 0][h], e1 = lw[wid][j + 1][h];
            float e2 = lw[wid][j + 2][h], e3 = lw[wid][j + 3][h];
            float e4 = lw[wid][j + 4][h], e5 = lw[wid][j + 5][h];
            float e6 = lw[wid][j + 6][h], e7 = lw[wid][j + 7][h];
            int4 sv0 = *(const int4*)&loff[wid][j];      // uniform broadcast
            int4 sv1 = *(const int4*)&loff[wid][j + 4];
            uint g0 = *(const uint*)(xpB + ((uint)sv0.x + lane4));
            uint g1 = *(const uint*)(xpB + ((uint)sv0.y + lane4));
            uint g2 = *(const uint*)(xpB + ((uint)sv0.z + lane4));
            uint g3 = *(const uint*)(xpB + ((uint)sv0.w + lane4));
            uint g4 = *(const uint*)(xpB + ((uint)sv1.x + lane4));
            uint g5 = *(const uint*)(xpB + ((uint)sv1.y + lane4));
            uint g6 = *(const uint*)(xpB + ((uint)sv1.z + lane4));
            uint g7 = *(const uint*)(xpB + ((uint)sv1.w + lane4));
            den += ((e0 + e1) + (e2 + e3)) + ((e4 + e5) + (e6 + e7));
            acc0 = fmaf(e0, __uint_as_float(g0 << 16), acc0);
            acc1 = fmaf(e0, __uint_as_float(g0 & 0xffff0000u), acc1);
            acc0 = fmaf(e1, __uint_as_float(g1 << 16), acc0);
            acc1 = fmaf(e1, __uint_as_float(g1 & 0xffff0000u), acc1);
            acc0 = fmaf(e2, __uint_as_float(g2 << 16), acc0);
            acc1 = fmaf(e2, __uint_as_float(g2 & 0xffff0000u), acc1);
            acc0 = fmaf(e3, __uint_as_float(g3 << 16), acc0);
            acc1 = fmaf(e3, __uint_as_float(g3 & 0xffff0000u), acc1);
            acc0 = fmaf(e4, __uint_as_float(g4 << 16), acc0);
            acc1 = fmaf(e4, __uint_as_float(g4 & 0xffff0000u), acc1);
            acc0 = fmaf(e5, __uint_as_float(g5 << 16), acc0);
            acc1 = fmaf(e5, __uint_as_float(g5 & 0xffff0000u), acc1);
            acc0 = fmaf(e6, __uint_as_float(g6 << 16), acc0);
            acc1 = fmaf(e6, __uint_as_float(g6 & 0xffff0000u), acc1);
            acc0 = fmaf(e7, __uint_as_float(g7 << 16), acc0);
            acc1 = fmaf(e7, __uint_as_float(g7 & 0xffff0000u), acc1);
        }
    }
    float inv = 1.f / (den + 1e-12f);
    float2 b2 = ((const float2*)bias)[lane];
    float2 o;
    o.x = acc0 * inv + b2.x;
    o.y = acc1 * inv + b2.y;
    ((float2*)(out + (long)n * HD))[lane] = o;
}

extern "C" void kernel_launch(void* const* d_in, const int* in_sizes, int n_in,
                              void* d_out, int out_size, void* d_ws, size_t ws_size,
                              hipStream_t stream) {
    const float* x = (const float*)d_in[0];
    const int* ei = (const int*)d_in[1];
    const float* W = (const float*)d_in[2];
    const float* att_src = (const float*)d_in[3];
    const float* att_dst = (const float*)d_in[4];
    const float* bias = (const float*)d_in[5];
    float* out = (float*)d_out;
    char* ws = (char*)d_ws;

    // workspace layout (bytes), 16B-aligned
    ushort* xp       = (ushort*)(ws + 0);         // 25,600,000 (bf16 x_proj)
    float* asrc      = (float*)(ws + 25600000);   //  1,600,000
    float* adst      = (float*)(ws + 27200000);   //  1,600,000
    int* esrc        = (int*)(ws + 28800000);     //  6,400,000
    int* rank        = (int*)(ws + 35200000);     //  6,400,000
    int* cnt         = (int*)(ws + 41600000);     //    400,000
    int* row_start   = (int*)(ws + 42000000);     //    400,004
    int* partial     = (int*)(ws + 42400016);     //        512
    // total ~42.4 MB

    hipMemsetAsync(cnt, 0, N_NODES * sizeof(int), stream);
    k_gemm_count<<<GEMM_BLKS + COUNT_BLKS, 256, 0, stream>>>(x, W, xp, att_src, att_dst,
                                                             asrc, adst, ei, cnt, rank);
    k_scan1<<<SCAN_NBLK, 256, 0, stream>>>(cnt, row_start, partial);
    k_scan3<<<(N_NODES + 255) / 256, 256, 0, stream>>>(row_start, partial);
    k_scatter<<<(N_EDGES + 255) / 256, 256, 0, stream>>>(ei, row_start, rank, esrc);
    k_aggregate<<<(N_NODES + 3) / 4, 256, 0, stream>>>(row_start, esrc,
                                                       (const char*)asrc, (const float4*)adst,
                                                       (const char*)xp, bias, out);
}

// Round 9
// 203.268 us; speedup vs baseline: 1.7184x; 1.0168x over previous
//
#include <hip/hip_runtime.h>
#include <math.h>

#define N_NODES 100000
#define N_EDGES 1600000
#define IN_DIM 128
#define HEADS 4
#define OUT_DIM 32
#define HD 128  // HEADS*OUT_DIM
#define NEG_SLOPE 0.2f
#define SCAN_NBLK 98    // ceil(100000/1024)
#define GEMM_BLKS 1563  // ceil(100000/64); also covers 1563*1024 >= 1.6M edges

typedef __attribute__((ext_vector_type(8))) short short8;
typedef __attribute__((ext_vector_type(4))) float f32x4;

__device__ inline ushort f2bf(float f) {
    // round-to-nearest-even fp32 -> bf16
    uint u = __float_as_uint(f);
    u += 0x7fffu + ((u >> 16) & 1u);
    return (ushort)(u >> 16);
}

// ---------------- K1: wave-specialized fusion: gemm (waves 0-3) + count (waves 4-7) ----------
// 512-thread block. Waves 0-3: x_proj = x @ W^T (bf16 MFMA, fused att-dots), 64 rows.
// Waves 4-7: per-dst histogram + within-segment rank for this block's 1024-edge slice
// (atomic return value IS the rank). Count waves execute 3 matching __syncthreads()
// up front (barrier pairing), then run their atomics while gemm waves use MFMA/LDS
// pipes -- both paths keep full CU residency (3 blocks/CU x 8 waves = 24 waves/CU).
__global__ __launch_bounds__(512) void k_gemm_count(const float* __restrict__ x,
                                                    const float* __restrict__ W,
                                                    ushort* __restrict__ xp,
                                                    const float* __restrict__ att_src,
                                                    const float* __restrict__ att_dst,
                                                    float* __restrict__ asrc,
                                                    float* __restrict__ adst,
                                                    const int* __restrict__ ei,
                                                    int* __restrict__ cnt,
                                                    int* __restrict__ rank) {
    __shared__ ushort lA[64 * 128];   // 16 KB
    __shared__ ushort lB[128 * 128];  // 32 KB
    const int tid = threadIdx.x;

    if (tid >= 256) {
        // ---------- count path (waves 4-7) ----------
        __syncthreads();  // pair with gemm barrier 1
        __syncthreads();  // pair with gemm barrier 2
        __syncthreads();  // pair with gemm barrier 3
        int e = blockIdx.x * 1024 + (tid - 256) * 4;
        if (e + 4 <= N_EDGES) {
            int4 d = *(const int4*)(ei + N_EDGES + e);
            int r0 = atomicAdd(&cnt[d.x], 1);
            int r1 = atomicAdd(&cnt[d.y], 1);
            int r2 = atomicAdd(&cnt[d.z], 1);
            int r3 = atomicAdd(&cnt[d.w], 1);
            *(int4*)(rank + e) = make_int4(r0, r1, r2, r3);
        } else {
            for (; e < N_EDGES; e++) rank[e] = atomicAdd(&cnt[ei[N_EDGES + e]], 1);
        }
        return;
    }

    // ---------- gemm path (waves 0-3) ----------
    const long row_base = (long)blockIdx.x * 64;

    // ---- stage A (x rows, fp32 -> bf16, swizzled) ----
    {
        const int r = tid >> 2;
        const int c0 = (tid & 3) * 32;
        const long row = row_base + r;
        const float* src = x + row * IN_DIM + c0;
#pragma unroll
        for (int i = 0; i < 4; i++) {  // 8 cols per iter
            float4 va, vb;
            if (row < N_NODES) {
                va = *(const float4*)(src + 8 * i);
                vb = *(const float4*)(src + 8 * i + 4);
            } else {
                va = make_float4(0.f, 0.f, 0.f, 0.f);
                vb = va;
            }
            ushort h[8] = {f2bf(va.x), f2bf(va.y), f2bf(va.z), f2bf(va.w),
                           f2bf(vb.x), f2bf(vb.y), f2bf(vb.z), f2bf(vb.w)};
            uint byte = (uint)(r * 256 + (c0 + 8 * i) * 2);
            byte ^= (uint)((r & 7) << 4);
            *(uint4*)((char*)lA + byte) = *(const uint4*)h;
        }
    }
    // ---- stage B (W rows, fp32 -> bf16, swizzled): lB[c][k] = W[c][k] ----
    {
        const int c = tid >> 1;
        const int k0 = (tid & 1) * 64;
        const float* src = W + c * IN_DIM + k0;
#pragma unroll
        for (int i = 0; i < 8; i++) {  // 8 k per iter
            float4 va = *(const float4*)(src + 8 * i);
            float4 vb = *(const float4*)(src + 8 * i + 4);
            ushort h[8] = {f2bf(va.x), f2bf(va.y), f2bf(va.z), f2bf(va.w),
                           f2bf(vb.x), f2bf(vb.y), f2bf(vb.z), f2bf(vb.w)};
            uint byte = (uint)(c * 256 + (k0 + 8 * i) * 2);
            byte ^= (uint)((c & 7) << 4);
            *(uint4*)((char*)lB + byte) = *(const uint4*)h;
        }
    }
    __syncthreads();  // barrier 1

    // ---- MFMA main: wave w owns rows w*16..w*16+15, all 128 cols ----
    const int w = tid >> 6;
    const int lane = tid & 63;
    const int l15 = lane & 15;
    const int g8 = (lane >> 4) * 8;  // k sub-offset (consistent convention for A and B)
    const int arow = w * 16 + l15;

    f32x4 acc[8];
#pragma unroll
    for (int nt = 0; nt < 8; nt++) acc[nt] = (f32x4){0.f, 0.f, 0.f, 0.f};

#pragma unroll
    for (int t = 0; t < 4; t++) {
        uint ab = (uint)(arow * 256 + (t * 32 + g8) * 2);
        ab ^= (uint)((arow & 7) << 4);
        short8 af = *(const short8*)((const char*)lA + ab);
#pragma unroll
        for (int nt = 0; nt < 8; nt++) {
            int c = nt * 16 + l15;
            uint bb = (uint)(c * 256 + (t * 32 + g8) * 2);
            bb ^= (uint)((c & 7) << 4);
            short8 bfr = *(const short8*)((const char*)lB + bb);
            acc[nt] = __builtin_amdgcn_mfma_f32_16x16x32_bf16(af, bfr, acc[nt], 0, 0, 0);
        }
    }
    __syncthreads();  // barrier 2: done reading lA/lB; reuse lA as out-tile

    // ---- write acc -> lA (linear [64][128] bf16 out-tile) ----
    // C/D layout: col = lane&15, row = 4*(lane>>4)+reg  [m89/m91]
    {
        const int m4 = 4 * (lane >> 4);
#pragma unroll
        for (int nt = 0; nt < 8; nt++) {
            int c = nt * 16 + l15;
#pragma unroll
            for (int r = 0; r < 4; r++) {
                lA[(w * 16 + m4 + r) * 128 + c] = f2bf(acc[nt][r]);
            }
        }
    }
    __syncthreads();  // barrier 3

    // ---- epilogue: coalesced xp store + fused attention dots ----
    {
        const int r = tid >> 2;
        const long node = row_base + r;
        if (node < N_NODES) {
            const int h = tid & 3;
            const int c0 = h * 32;
            const uint4* s = (const uint4*)(lA + r * 128 + c0);
            uint4 v0 = s[0], v1 = s[1], v2 = s[2], v3 = s[3];
            uint4* d = (uint4*)(xp + node * HD + c0);
            d[0] = v0; d[1] = v1; d[2] = v2; d[3] = v3;
            // att dots over this head's 32 cols (values already in regs)
            const float* as = att_src + c0;
            const float* ad = att_dst + c0;
            float s0 = 0.f, s1 = 0.f;
            uint4 vv[4] = {v0, v1, v2, v3};
#pragma unroll
            for (int q = 0; q < 4; q++) {
                const uint* u = (const uint*)&vv[q];
#pragma unroll
                for (int p = 0; p < 4; p++) {
                    float f0 = __uint_as_float((u[p] & 0xffffu) << 16);
                    float f1 = __uint_as_float(u[p] & 0xffff0000u);
                    int cc = q * 8 + p * 2;
                    s0 = fmaf(f0, as[cc], s0);
                    s0 = fmaf(f1, as[cc + 1], s0);
                    s1 = fmaf(f0, ad[cc], s1);
                    s1 = fmaf(f1, ad[cc + 1], s1);
                }
            }
            asrc[node * HEADS + h] = s0;
            adst[node * HEADS + h] = s1;
        }
    }
}

// ---------------- K3a: block-level exclusive scan of counts ----------------
__global__ __launch_bounds__(256) void k_scan1(const int* __restrict__ cnt,
                                               int* __restrict__ row_start,
                                               int* __restrict__ partial) {
    __shared__ int lds[256];
    int t = threadIdx.x;
    int base = blockIdx.x * 1024 + t * 4;
    int c0 = (base + 0 < N_NODES) ? cnt[base + 0] : 0;
    int c1 = (base + 1 < N_NODES) ? cnt[base + 1] : 0;
    int c2 = (base + 2 < N_NODES) ? cnt[base + 2] : 0;
    int c3 = (base + 3 < N_NODES) ? cnt[base + 3] : 0;
    int p1 = c0, p2 = c0 + c1, p3 = c0 + c1 + c2;
    int tsum = p3 + c3;
    lds[t] = tsum;
    __syncthreads();
    for (int off = 1; off < 256; off <<= 1) {
        int v = (t >= off) ? lds[t - off] : 0;
        __syncthreads();
        lds[t] += v;
        __syncthreads();
    }
    int excl = (t == 0) ? 0 : lds[t - 1];
    if (base + 0 < N_NODES) row_start[base + 0] = excl;
    if (base + 1 < N_NODES) row_start[base + 1] = excl + p1;
    if (base + 2 < N_NODES) row_start[base + 2] = excl + p2;
    if (base + 3 < N_NODES) row_start[base + 3] = excl + p3;
    if (t == 255) partial[blockIdx.x] = lds[255];
}

// ---------------- K3b: apply block prefixes (scan of <=98 partials done in-block) ----------------
__global__ __launch_bounds__(256) void k_scan3(int* __restrict__ row_start,
                                               const int* __restrict__ partial) {
    __shared__ int sprefix;
    const int b = blockIdx.x;
    const int g = b >> 2;  // 1024-node group; uniform per 256-node block
    const int t = threadIdx.x;
    if (t < 64) {
        int p = (t < g) ? partial[t] : 0;
        if (t + 64 < g) p += partial[t + 64];
#pragma unroll
        for (int off = 32; off > 0; off >>= 1) p += __shfl_down(p, off);
        if (t == 0) sprefix = p;
    }
    __syncthreads();
    int i = b * 256 + t;
    if (i < N_NODES) row_start[i] += sprefix;
    if (i == 0) row_start[N_NODES] = N_EDGES;
}

// ---------------- K4: atomic-free CSR scatter, single pass ----------------
// esrc stores PRE-SHIFTED byte offsets (src*256 = src row offset in bf16 xp),
// so aggregate's per-edge address math is a single 32-bit add.
__global__ void k_scatter(const int* __restrict__ ei,
                          const int* __restrict__ row_start,
                          const int* __restrict__ rank,
                          int* __restrict__ esrc) {
    int e = blockIdx.x * 256 + threadIdx.x;
    if (e >= N_EDGES) return;
    int d = ei[N_EDGES + e];
    esrc[row_start[d] + rank[e]] = ei[e] << 8;
}

// ---------------- K5: single-pass softmax + aggregation (1 wave/node) ----------------
// xp is bf16; lane owns output elements {2*lane, 2*lane+1} (head h=lane>>4): each
// edge's row gather is ONE dword-per-lane saddr load (256 B/wave = 1 row).
// Per 64-edge chunk: every lane stages {4 head-weights, byte-offset} in per-wave LDS
// (invalid lanes stage weight 0, offset 0 -> contribute nothing), so the inner loop
// runs 8-wide with NO tail: 8 gathers in flight, ~7 VALU/edge.
__global__ __launch_bounds__(256) void k_aggregate(const int* __restrict__ row_start,
                                                   const int* __restrict__ esrc,
                                                   const char* __restrict__ asrcB,
                                                   const float4* __restrict__ adst4,
                                                   const char* __restrict__ xpB,
                                                   const float* __restrict__ bias,
                                                   float* __restrict__ out) {
    __shared__ float lw[4][64][4];  // [wave][edge][head] weights
    __shared__ int loff[4][64];     // [wave][edge] xp byte offsets
    const int wid = threadIdx.x >> 6;
    const int lane = threadIdx.x & 63;
    const int n = blockIdx.x * 4 + wid;
    if (n >= N_NODES) return;
    const int s0 = row_start[n];
    const int s1 = row_start[n + 1];
    const int h = lane >> 4;
    const uint lane4 = (uint)lane * 4;
    const float4 ad = adst4[n];  // wave-uniform

    float acc0 = 0.f, acc1 = 0.f, den = 0.f;

    for (int base = s0; base < s1; base += 64) {
        const int rem = s1 - base;
        const int cnt = rem < 64 ? rem : 64;
        const bool v = lane < cnt;
        int moff = v ? esrc[base + lane] : 0;  // src*256 (byte offset)
        float4 as = *(const float4*)(asrcB + (moff >> 4));  // src*16
        float tx = as.x + ad.x, ty = as.y + ad.y, tz = as.z + ad.z, tw = as.w + ad.w;
        tx = (tx >= 0.f) ? tx : NEG_SLOPE * tx;
        ty = (ty >= 0.f) ? ty : NEG_SLOPE * ty;
        tz = (tz >= 0.f) ? tz : NEG_SLOPE * tz;
        tw = (tw >= 0.f) ? tw : NEG_SLOPE * tw;
        float4 wv;
        wv.x = v ? __expf(fminf(tx, 80.f)) : 0.f;
        wv.y = v ? __expf(fminf(ty, 80.f)) : 0.f;
        wv.z = v ? __expf(fminf(tz, 80.f)) : 0.f;
        wv.w = v ? __expf(fminf(tw, 80.f)) : 0.f;
        loff[wid][lane] = moff;
        *(float4*)&lw[wid][lane][0] = wv;
        // same-wave LDS staging: compiler inserts lgkmcnt ordering

        const int cnt8 = (cnt + 7) & ~7;  // padded: dummy edges have weight 0
        for (int j = 0; j < cnt8; j += 8) {
            float e0 = lw[wid][j + 0][h], e1 = lw[wid][j + 1][h];
            float e2 = lw[wid][j + 2][h], e3 = lw[wid][j + 3][h];
            float e4 = lw[wid][j + 4][h], e5 = lw[wid][j + 5][h];
            float e6 = lw[wid][j + 6][h], e7 = lw[wid][j + 7][h];
            int4 sv0 = *(const int4*)&loff[wid][j];      // uniform broadcast
            int4 sv1 = *(const int4*)&loff[wid][j + 4];
            uint g0 = *(const uint*)(xpB + ((uint)sv0.x + lane4));
            uint g1 = *(const uint*)(xpB + ((uint)sv0.y + lane4));
            uint g2 = *(const uint*)(xpB + ((uint)sv0.z + lane4));
            uint g3 = *(const uint*)(xpB + ((uint)sv0.w + lane4));
            uint g4 = *(const uint*)(xpB + ((uint)sv1.x + lane4));
            uint g5 = *(const uint*)(xpB + ((uint)sv1.y + lane4));
            uint g6 = *(const uint*)(xpB + ((uint)sv1.z + lane4));
            uint g7 = *(const uint*)(xpB + ((uint)sv1.w + lane4));
            den += ((e0 + e1) + (e2 + e3)) + ((e4 + e5) + (e6 + e7));
            acc0 = fmaf(e0, __uint_as_float(g0 << 16), acc0);
            acc1 = fmaf(e0, __uint_as_float(g0 & 0xffff0000u), acc1);
            acc0 = fmaf(e1, __uint_as_float(g1 << 16), acc0);
            acc1 = fmaf(e1, __uint_as_float(g1 & 0xffff0000u), acc1);
            acc0 = fmaf(e2, __uint_as_float(g2 << 16), acc0);
            acc1 = fmaf(e2, __uint_as_float(g2 & 0xffff0000u), acc1);
            acc0 = fmaf(e3, __uint_as_float(g3 << 16), acc0);
            acc1 = fmaf(e3, __uint_as_float(g3 & 0xffff0000u), acc1);
            acc0 = fmaf(e4, __uint_as_float(g4 << 16), acc0);
            acc1 = fmaf(e4, __uint_as_float(g4 & 0xffff0000u), acc1);
            acc0 = fmaf(e5, __uint_as_float(g5 << 16), acc0);
            acc1 = fmaf(e5, __uint_as_float(g5 & 0xffff0000u), acc1);
            acc0 = fmaf(e6, __uint_as_float(g6 << 16), acc0);
            acc1 = fmaf(e6, __uint_as_float(g6 & 0xffff0000u), acc1);
            acc0 = fmaf(e7, __uint_as_float(g7 << 16), acc0);
            acc1 = fmaf(e7, __uint_as_float(g7 & 0xffff0000u), acc1);
        }
    }
    float inv = 1.f / (den + 1e-12f);
    float2 b2 = ((const float2*)bias)[lane];
    float2 o;
    o.x = acc0 * inv + b2.x;
    o.y = acc1 * inv + b2.y;
    ((float2*)(out + (long)n * HD))[lane] = o;
}

extern "C" void kernel_launch(void* const* d_in, const int* in_sizes, int n_in,
                              void* d_out, int out_size, void* d_ws, size_t ws_size,
                              hipStream_t stream) {
    const float* x = (const float*)d_in[0];
    const int* ei = (const int*)d_in[1];
    const float* W = (const float*)d_in[2];
    const float* att_src = (const float*)d_in[3];
    const float* att_dst = (const float*)d_in[4];
    const float* bias = (const float*)d_in[5];
    float* out = (float*)d_out;
    char* ws = (char*)d_ws;

    // workspace layout (bytes), 16B-aligned
    ushort* xp       = (ushort*)(ws + 0);         // 25,600,000 (bf16 x_proj)
    float* asrc      = (float*)(ws + 25600000);   //  1,600,000
    float* adst      = (float*)(ws + 27200000);   //  1,600,000
    int* esrc        = (int*)(ws + 28800000);     //  6,400,000
    int* rank        = (int*)(ws + 35200000);     //  6,400,000
    int* cnt         = (int*)(ws + 41600000);     //    400,000
    int* row_start   = (int*)(ws + 42000000);     //    400,004
    int* partial     = (int*)(ws + 42400016);     //        512
    // total ~42.4 MB

    hipMemsetAsync(cnt, 0, N_NODES * sizeof(int), stream);
    k_gemm_count<<<GEMM_BLKS, 512, 0, stream>>>(x, W, xp, att_src, att_dst,
                                                asrc, adst, ei, cnt, rank);
    k_scan1<<<SCAN_NBLK, 256, 0, stream>>>(cnt, row_start, partial);
    k_scan3<<<(N_NODES + 255) / 256, 256, 0, stream>>>(row_start, partial);
    k_scatter<<<(N_EDGES + 255) / 256, 256, 0, stream>>>(ei, row_start, rank, esrc);
    k_aggregate<<<(N_NODES + 3) / 4, 256, 0, stream>>>(row_start, esrc,
                                                       (const char*)asrc, (const float4*)adst,
                                                       (const char*)xp, bias, out);
}